// Round 1
// baseline (4892.742 us; speedup 1.0000x reference)
//
#include <hip/hip_runtime.h>

#define BB 16
#define TZ_ 2048
#define TT_ 512
#define D_ 256
#define DFF_ 1024
#define L_ 6
#define HEADS_ 4
#define DH_ 64
#define CH_ 256
#define HID_ 256
#define KCV 5
#define FLOWS_ 4
#define G_ 256
#define NEGF (-1000000000.0f)
#define LOG2PI 1.8378770664093453f

__device__ __forceinline__ float wsum(float v){
#pragma unroll
  for (int o = 32; o; o >>= 1) v += __shfl_xor(v, o);
  return v;
}

// ---------------- positional encoding (f64, matches np) ----------------
__global__ void k_pe(float* __restrict__ pe){
  int t = blockIdx.x, d = threadIdx.x;
  double e = (double)(2*(d>>1)) / (double)D_;
  double ang = (double)t * pow(10000.0, -e);
  pe[t*D_ + d] = (float)(((d&1)==0) ? sin(ang) : cos(ang));
}

// ---------------- embedding ----------------
__global__ void k_embed(const int* __restrict__ text, const float* __restrict__ emb,
                        const float* __restrict__ pe, float* __restrict__ h){
  int row = blockIdx.x, d = threadIdx.x;
  h[(size_t)row*D_ + d] = emb[(size_t)text[row]*D_ + d]*16.0f + pe[(row%TT_)*D_ + d];
}

// ---------------- generic tiled f32 GEMM: C = A[M,K]@W[K,N] + bias (+bias2 per row-group) ----------------
// block 256 thr -> 64x64 tile, 4x4 per thread, K-tiles of 16.
template<int RELU>
__global__ __launch_bounds__(256,2) void k_gemm(
  const float* __restrict__ A, int lda,
  const float* __restrict__ W, int ldw,
  const float* __restrict__ bias,
  const float* __restrict__ bias2, int b2rows,  // bias2[(row/b2rows)*ldc + col], may be null
  float* __restrict__ C, int ldc, int K)
{
  __shared__ float As[16][64];
  __shared__ float Ws[16][64];
  const int t  = threadIdx.x;
  const int tx = t & 15, ty = t >> 4;
  const size_t row0 = (size_t)blockIdx.y * 64;
  const size_t col0 = (size_t)blockIdx.x * 64;
  const int arow = t >> 2, ak4 = (t & 3) << 2;
  const int wk = t >> 4, wc4 = (t & 15) << 2;
  float acc[4][4] = {};
  for (int k0 = 0; k0 < K; k0 += 16){
    __syncthreads();
    float4 av = *(const float4*)(A + (row0 + arow)*lda + k0 + ak4);
    As[ak4+0][arow]=av.x; As[ak4+1][arow]=av.y; As[ak4+2][arow]=av.z; As[ak4+3][arow]=av.w;
    *(float4*)&Ws[wk][wc4] = *(const float4*)(W + (size_t)(k0+wk)*ldw + col0 + wc4);
    __syncthreads();
#pragma unroll
    for (int kk=0;kk<16;kk++){
      float4 a4 = *(const float4*)&As[kk][ty<<2];
      float4 w4 = *(const float4*)&Ws[kk][tx<<2];
      float ar[4]={a4.x,a4.y,a4.z,a4.w}, wr[4]={w4.x,w4.y,w4.z,w4.w};
#pragma unroll
      for (int i=0;i<4;i++)
#pragma unroll
        for (int j=0;j<4;j++)
          acc[i][j] = fmaf(ar[i], wr[j], acc[i][j]);
    }
  }
#pragma unroll
  for (int i=0;i<4;i++){
    size_t r = row0 + (ty<<2) + i;
#pragma unroll
    for (int j=0;j<4;j++){
      size_t c = col0 + (tx<<2) + j;
      float v = acc[i][j];
      if (bias)  v += bias[c];
      if (bias2) v += bias2[(r / (size_t)b2rows)*ldc + c];
      if (RELU)  v = fmaxf(v, 0.0f);
      C[r*ldc + c] = v;
    }
  }
}

// ---------------- attention scores: S[bh,i,j] = q.k/8 + mask-bias ----------------
__global__ __launch_bounds__(256,2) void k_scores(
  const float* __restrict__ q, const float* __restrict__ k,
  const int* __restrict__ text, float* __restrict__ S)
{
  const int bh = blockIdx.z, b = bh >> 2, h = bh & 3;
  const float* qb = q + (size_t)b*TT_*D_ + h*DH_;
  const float* kb = k + (size_t)b*TT_*D_ + h*DH_;
  __shared__ float Qs[16][64], Ks[16][64];
  const int t = threadIdx.x, tx = t&15, ty = t>>4;
  const int i0 = blockIdx.y*64, j0 = blockIdx.x*64;
  const int arow = t>>2, ak4 = (t&3)<<2;
  float acc[4][4] = {};
  for (int k0=0;k0<DH_;k0+=16){
    __syncthreads();
    float4 av = *(const float4*)(qb + (size_t)(i0+arow)*D_ + k0+ak4);
    Qs[ak4+0][arow]=av.x; Qs[ak4+1][arow]=av.y; Qs[ak4+2][arow]=av.z; Qs[ak4+3][arow]=av.w;
    float4 bv = *(const float4*)(kb + (size_t)(j0+arow)*D_ + k0+ak4);
    Ks[ak4+0][arow]=bv.x; Ks[ak4+1][arow]=bv.y; Ks[ak4+2][arow]=bv.z; Ks[ak4+3][arow]=bv.w;
    __syncthreads();
#pragma unroll
    for (int kk=0;kk<16;kk++){
      float4 a4 = *(const float4*)&Qs[kk][ty<<2];
      float4 w4 = *(const float4*)&Ks[kk][tx<<2];
      float ar[4]={a4.x,a4.y,a4.z,a4.w}, wr[4]={w4.x,w4.y,w4.z,w4.w};
#pragma unroll
      for (int i=0;i<4;i++)
#pragma unroll
        for (int j=0;j<4;j++) acc[i][j] = fmaf(ar[i], wr[j], acc[i][j]);
    }
  }
#pragma unroll
  for (int i=0;i<4;i++){
    int ii = i0 + (ty<<2) + i;
#pragma unroll
    for (int j=0;j<4;j++){
      int jj = j0 + (tx<<2) + j;
      float bias = (text[b*TT_ + jj] != 0) ? 0.0f : NEGF;
      S[((size_t)bh*TT_ + ii)*TT_ + jj] = acc[i][j]*0.125f + bias;
    }
  }
}

// ---------------- row softmax over 512 (one wave per row) ----------------
__global__ __launch_bounds__(64) void k_softmax(float* __restrict__ S){
  size_t row = blockIdx.x;
  float* p = S + row*TT_;
  int ln = threadIdx.x;
  float4 a = *(float4*)(p + ln*8);
  float4 b = *(float4*)(p + ln*8 + 4);
  float x[8] = {a.x,a.y,a.z,a.w,b.x,b.y,b.z,b.w};
  float m = x[0];
#pragma unroll
  for (int i=1;i<8;i++) m = fmaxf(m, x[i]);
#pragma unroll
  for (int o2=32;o2;o2>>=1) m = fmaxf(m, __shfl_xor(m, o2));
  float s = 0.f;
#pragma unroll
  for (int i=0;i<8;i++){ x[i] = expf(x[i]-m); s += x[i]; }
  s = wsum(s);
  float inv = 1.0f/s;
  *(float4*)(p + ln*8)     = make_float4(x[0]*inv, x[1]*inv, x[2]*inv, x[3]*inv);
  *(float4*)(p + ln*8 + 4) = make_float4(x[4]*inv, x[5]*inv, x[6]*inv, x[7]*inv);
}

// ---------------- attn @ V -> (B,T,D) layout ----------------
__global__ __launch_bounds__(256,2) void k_av(const float* __restrict__ P,
  const float* __restrict__ v, float* __restrict__ out){
  const int bh = blockIdx.z, b = bh >> 2, h = bh & 3;
  const float* Pb = P + (size_t)bh*TT_*TT_;
  const float* vb = v + (size_t)b*TT_*D_ + h*DH_;
  const int t = threadIdx.x, tx=t&15, ty=t>>4;
  const int i0 = blockIdx.y*64;
  const int arow=t>>2, ak4=(t&3)<<2, wk=t>>4, wc4=(t&15)<<2;
  __shared__ float As[16][64], Ws[16][64];
  float acc[4][4]={};
  for (int k0=0;k0<TT_;k0+=16){
    __syncthreads();
    float4 av = *(const float4*)(Pb + (size_t)(i0+arow)*TT_ + k0+ak4);
    As[ak4+0][arow]=av.x; As[ak4+1][arow]=av.y; As[ak4+2][arow]=av.z; As[ak4+3][arow]=av.w;
    *(float4*)&Ws[wk][wc4] = *(const float4*)(vb + (size_t)(k0+wk)*D_ + wc4);
    __syncthreads();
#pragma unroll
    for (int kk=0;kk<16;kk++){
      float4 a4 = *(const float4*)&As[kk][ty<<2];
      float4 w4 = *(const float4*)&Ws[kk][tx<<2];
      float ar[4]={a4.x,a4.y,a4.z,a4.w}, wr[4]={w4.x,w4.y,w4.z,w4.w};
#pragma unroll
      for (int i=0;i<4;i++)
#pragma unroll
        for (int j=0;j<4;j++) acc[i][j] = fmaf(ar[i], wr[j], acc[i][j]);
    }
  }
#pragma unroll
  for (int i=0;i<4;i++){
    size_t r = (size_t)b*TT_ + i0 + (ty<<2) + i;
#pragma unroll
    for (int j=0;j<4;j++)
      out[r*D_ + h*DH_ + (tx<<2) + j] = acc[i][j];
  }
}

// ---------------- residual + LayerNorm (in-place on h) ----------------
__global__ __launch_bounds__(256) void k_lnres(const float* __restrict__ y,
  const float* __restrict__ g, const float* __restrict__ bb, float* __restrict__ h){
  size_t row = blockIdx.x; int d = threadIdx.x;
  float v = h[row*D_ + d] + y[row*D_ + d];
  float s = wsum(v), s2 = wsum(v*v);
  __shared__ float r1[4], r2[4];
  int w = d >> 6;
  if ((d & 63) == 0){ r1[w] = s; r2[w] = s2; }
  __syncthreads();
  s  = r1[0]+r1[1]+r1[2]+r1[3];
  s2 = r2[0]+r2[1]+r2[2]+r2[3];
  float mean = s * (1.0f/D_);
  float var  = s2 * (1.0f/D_) - mean*mean;
  float inv  = rsqrtf(var + 1e-6f);
  h[row*D_ + d] = g[d]*(v - mean)*inv + bb[d];
}

// ---------------- spr/msp/nc1/nc4 prep (lv buffer becomes spr) ----------------
__global__ __launch_bounds__(256) void k_prep(const float* __restrict__ mu, float* __restrict__ lv,
  float* __restrict__ msp, float* __restrict__ nc1, float* __restrict__ nc4){
  size_t row = blockIdx.x; int d = threadIdx.x;
  float l = lv[row*D_ + d];
  float m = mu[row*D_ + d];
  float sp = expf(-l);
  float s1 = wsum(l), s2 = wsum(m*m*sp);
  __shared__ float r1[4], r2[4];
  int w = d >> 6;
  if ((d&63)==0){ r1[w]=s1; r2[w]=s2; }
  __syncthreads();
  if (d == 0){
    nc1[row] = -0.5f*((float)D_*LOG2PI + (r1[0]+r1[1]+r1[2]+r1[3]));
    nc4[row] = -0.5f*(r2[0]+r2[1]+r2[2]+r2[3]);
  }
  lv[row*D_ + d]  = sp;
  msp[row*D_ + d] = m*sp;
}

// ---------------- cond @ flow_cond[f]  (16x256x256, tiny) ----------------
__global__ __launch_bounds__(256) void k_condproj(const float* __restrict__ cond,
  const float* __restrict__ W, float* __restrict__ out){
  const int b = blockIdx.x, n = threadIdx.x;
  float s = 0.f;
  for (int k2=0;k2<G_;k2++) s = fmaf(cond[b*G_ + k2], W[k2*HID_ + n], s);
  out[b*HID_ + n] = s;
}

// ---------------- conv1d K=5 SAME (NWC,WIO) + bias + tanh ----------------
__global__ __launch_bounds__(256,2) void k_conv(const float* __restrict__ X,
  const float* __restrict__ Wc, const float* __restrict__ bc, float* __restrict__ Y){
  const int b = blockIdx.z, t0 = blockIdx.y*64, o0 = blockIdx.x*64;
  const int t = threadIdx.x, tx=t&15, ty=t>>4;
  const int arow=t>>2, ak4=(t&3)<<2, wk=t>>4, wc4=(t&15)<<2;
  __shared__ float As[16][64], Ws[16][64];
  float acc[4][4]={};
  for (int w=0; w<KCV; w++){
    const float* Ww = Wc + (size_t)w*HID_*HID_;
    const int tt = t0 + arow + w - 2;
    const bool ok = (tt >= 0) && (tt < TZ_);
    for (int k0=0;k0<HID_;k0+=16){
      __syncthreads();
      float4 av = make_float4(0.f,0.f,0.f,0.f);
      if (ok) av = *(const float4*)(X + ((size_t)b*TZ_ + tt)*HID_ + k0+ak4);
      As[ak4+0][arow]=av.x; As[ak4+1][arow]=av.y; As[ak4+2][arow]=av.z; As[ak4+3][arow]=av.w;
      *(float4*)&Ws[wk][wc4] = *(const float4*)(Ww + (size_t)(k0+wk)*HID_ + o0+wc4);
      __syncthreads();
#pragma unroll
      for (int kk=0;kk<16;kk++){
        float4 a4 = *(const float4*)&As[kk][ty<<2];
        float4 w4 = *(const float4*)&Ws[kk][tx<<2];
        float ar[4]={a4.x,a4.y,a4.z,a4.w}, wr[4]={w4.x,w4.y,w4.z,w4.w};
#pragma unroll
        for (int i=0;i<4;i++)
#pragma unroll
          for (int j=0;j<4;j++) acc[i][j] = fmaf(ar[i], wr[j], acc[i][j]);
      }
    }
  }
#pragma unroll
  for (int i=0;i<4;i++){
    size_t r = (size_t)b*TZ_ + t0 + (ty<<2) + i;
#pragma unroll
    for (int j=0;j<4;j++){
      int c = o0 + (tx<<2) + j;
      Y[r*HID_ + c] = tanhf(acc[i][j] + bc[c]);
    }
  }
}

// ---------------- flow coupling recombine: dst = [x1 + m, x0] ----------------
__global__ void k_flowmix(const float* __restrict__ src, const float* __restrict__ m,
                          float* __restrict__ dst){
  size_t i = (size_t)blockIdx.x*256 + threadIdx.x;
  size_t row = i >> 8; int c = (int)(i & 255);
  float val;
  if (c < 128) val = src[row*CH_ + 128 + c] + m[row*(CH_/2) + c];
  else         val = src[row*CH_ + c - 128];
  dst[i] = val;
}

// ---------------- logp[b,t,j] = nc1+nc4 + zc.(mu*spr) - 0.5*zc^2.spr ----------------
__global__ __launch_bounds__(256,2) void k_logp(const float* __restrict__ zc,
  const float* __restrict__ msp, const float* __restrict__ spr,
  const float* __restrict__ nc1, const float* __restrict__ nc4,
  const int* __restrict__ text, float* __restrict__ lp){
  const int b = blockIdx.z, t0 = blockIdx.y*64, j0 = blockIdx.x*64;
  const int t = threadIdx.x, tx=t&15, ty=t>>4;
  const int arow=t>>2, ak4=(t&3)<<2;
  __shared__ float As[16][64], Ms[16][64], Ss[16][64];
  float acc[4][4]={};
  for (int k0=0;k0<D_;k0+=16){
    __syncthreads();
    float4 av = *(const float4*)(zc + ((size_t)b*TZ_ + t0+arow)*CH_ + k0+ak4);
    As[ak4+0][arow]=av.x; As[ak4+1][arow]=av.y; As[ak4+2][arow]=av.z; As[ak4+3][arow]=av.w;
    float4 mv = *(const float4*)(msp + ((size_t)b*TT_ + j0+arow)*D_ + k0+ak4);
    Ms[ak4+0][arow]=mv.x; Ms[ak4+1][arow]=mv.y; Ms[ak4+2][arow]=mv.z; Ms[ak4+3][arow]=mv.w;
    float4 sv = *(const float4*)(spr + ((size_t)b*TT_ + j0+arow)*D_ + k0+ak4);
    Ss[ak4+0][arow]=sv.x; Ss[ak4+1][arow]=sv.y; Ss[ak4+2][arow]=sv.z; Ss[ak4+3][arow]=sv.w;
    __syncthreads();
#pragma unroll
    for (int kk=0;kk<16;kk++){
      float4 a4 = *(const float4*)&As[kk][ty<<2];
      float4 m4 = *(const float4*)&Ms[kk][tx<<2];
      float4 s4 = *(const float4*)&Ss[kk][tx<<2];
      float ar[4]={a4.x,a4.y,a4.z,a4.w};
      float h2[4];
#pragma unroll
      for (int i=0;i<4;i++) h2[i] = -0.5f*ar[i]*ar[i];
      float mr[4]={m4.x,m4.y,m4.z,m4.w}, sr[4]={s4.x,s4.y,s4.z,s4.w};
#pragma unroll
      for (int i=0;i<4;i++)
#pragma unroll
        for (int j=0;j<4;j++)
          acc[i][j] = fmaf(ar[i], mr[j], fmaf(h2[i], sr[j], acc[i][j]));
    }
  }
#pragma unroll
  for (int j=0;j<4;j++){
    int jj = j0 + (tx<<2) + j;
    float base = nc1[b*TT_ + jj] + nc4[b*TT_ + jj];
    bool msk = (text[b*TT_ + jj] != 0);
#pragma unroll
    for (int i=0;i<4;i++){
      size_t r = (size_t)b*TZ_ + t0 + (ty<<2) + i;
      lp[r*TT_ + jj] = msk ? (acc[i][j] + base) : NEGF;
    }
  }
}

// ---------------- MAS: (max,+) forward scan + backtrack. one wave per batch ----------------
__global__ __launch_bounds__(64) void k_mas(const float* __restrict__ lp,
  const int* __restrict__ text, unsigned char* __restrict__ cho, int* __restrict__ path){
  const int b = blockIdx.x, ln = threadIdx.x;
  const float* L = lp + (size_t)b*TZ_*TT_;
  int cnt = 0;
#pragma unroll
  for (int i=0;i<8;i++) cnt += (text[b*TT_ + ln*8 + i] != 0) ? 1 : 0;
#pragma unroll
  for (int o2=32;o2;o2>>=1) cnt += __shfl_xor(cnt, o2);
  const int jlast = cnt - 1;
  float Q[8];
#pragma unroll
  for (int i=0;i<8;i++) Q[i] = NEGF;
  if (ln == 0) Q[0] = L[0];
  unsigned char* cb = cho + (size_t)b*TZ_*64;
  for (int t2=1; t2<TZ_; t2++){
    const float* lt = L + (size_t)t2*TT_ + ln*8;
    float4 u0 = *(const float4*)lt;
    float4 u1 = *(const float4*)(lt+4);
    float v[8] = {u0.x,u0.y,u0.z,u0.w,u1.x,u1.y,u1.z,u1.w};
    float qp = __shfl_up(Q[7], 1);
    if (ln == 0) qp = NEGF;
    unsigned bits = 0; float qs = qp;
#pragma unroll
    for (int i=0;i<8;i++){
      float old = Q[i];
      if (qs > old) bits |= (1u<<i);
      Q[i] = v[i] + fmaxf(old, qs);
      qs = old;
    }
    cb[(size_t)(t2-1)*64 + ln] = (unsigned char)bits;
  }
  __shared__ unsigned char lch[64*64];
  int j = jlast;
  if (ln == 0) path[b*TZ_ + TZ_-1] = j;
  __syncthreads();
  for (int tc = TZ_-1; tc >= 1; tc -= 64){
    int ns = min(64, tc);
    for (int s=0;s<ns;s++) lch[s*64 + ln] = cb[(size_t)(tc-1-s)*64 + ln];
    __syncthreads();
    if (ln == 0){
      for (int s=0;s<ns;s++){
        int t2 = tc - s;
        unsigned bits = lch[s*64 + (j>>3)];
        j -= (int)((bits >> (j&7)) & 1u);
        path[b*TZ_ + t2 - 1] = j;
      }
    }
    __syncthreads();
  }
}

// ---------------- ctx gather + h copy into d_out ----------------
__global__ void k_gather(const float* __restrict__ mu, const int* __restrict__ path,
  const float* __restrict__ h, float* __restrict__ out){
  size_t i = (size_t)blockIdx.x*256 + threadIdx.x;
  const size_t N4 = (size_t)BB*TZ_*(D_/4);
  const size_t H4 = (size_t)BB*TT_*(D_/4);
  if (i < N4){
    size_t row = i >> 6; int c = (int)(i & 63);
    int b = (int)(row >> 11);
    int pj = path[row];
    ((float4*)out)[i] = *(const float4*)(mu + ((size_t)b*TT_ + pj)*D_ + (size_t)c*4);
  } else if (i < N4 + H4){
    size_t k2 = i - N4;
    ((float4*)out)[i] = ((const float4*)h)[k2];
  }
}

extern "C" void kernel_launch(void* const* d_in, const int* in_sizes, int n_in,
                              void* d_out, int out_size, void* d_ws, size_t ws_size,
                              hipStream_t stream)
{
  (void)in_sizes; (void)n_in; (void)out_size; (void)ws_size;
  const float* z      = (const float*)d_in[0];
  const int*   text   = (const int*)  d_in[1];
  const float* cond   = (const float*)d_in[2];
  const float* emb    = (const float*)d_in[3];
  const float* wq     = (const float*)d_in[4];
  const float* wk     = (const float*)d_in[5];
  const float* wv     = (const float*)d_in[6];
  const float* wo     = (const float*)d_in[7];
  const float* bq     = (const float*)d_in[8];
  const float* bk     = (const float*)d_in[9];
  const float* bv     = (const float*)d_in[10];
  const float* bo     = (const float*)d_in[11];
  const float* ln1g   = (const float*)d_in[12];
  const float* ln1b   = (const float*)d_in[13];
  const float* ln2g   = (const float*)d_in[14];
  const float* ln2b   = (const float*)d_in[15];
  const float* w1     = (const float*)d_in[16];
  const float* b1     = (const float*)d_in[17];
  const float* w2     = (const float*)d_in[18];
  const float* b2     = (const float*)d_in[19];
  const float* mu_w   = (const float*)d_in[20];
  const float* mu_b   = (const float*)d_in[21];
  const float* lv_w   = (const float*)d_in[22];
  const float* lv_b   = (const float*)d_in[23];
  const float* f_in   = (const float*)d_in[24];
  const float* f_in_b = (const float*)d_in[25];
  const float* f_cond = (const float*)d_in[26];
  const float* f_conv = (const float*)d_in[27];
  const float* f_convb= (const float*)d_in[28];
  const float* f_out  = (const float*)d_in[29];
  const float* f_outb = (const float*)d_in[30];

  float* ws = (float*)d_ws;
  size_t o = 0;
  float* PE   = ws + o; o += (size_t)TT_*D_;
  float* H    = ws + o; o += (size_t)BB*TT_*D_;
  float* MU   = ws + o; o += (size_t)BB*TT_*D_;
  float* SPR  = ws + o; o += (size_t)BB*TT_*D_;   // logvar, then spr
  float* MSP  = ws + o; o += (size_t)BB*TT_*D_;
  float* NC1  = ws + o; o += (size_t)BB*TT_;
  float* NC4  = ws + o; o += (size_t)BB*TT_;
  float* CONDP= ws + o; o += (size_t)BB*HID_;
  int*   PATH = (int*)(ws + o); o += (size_t)BB*TZ_;
  float* BIGS = ws + o; o += (size_t)BB*HEADS_*TT_*TT_;  // scores, later logp (same size)
  float* BUF1 = ws + o; o += (size_t)BB*TT_*DFF_;        // ffn tmp / flow hh1 / flow m
  float* BUF2 = ws + o; o += (size_t)BB*TZ_*HID_;        // q,k,v,y (4 x B*TT*D) / flow hh2
  float* ZCA  = ws + o; o += (size_t)BB*TZ_*CH_;
  float* ZCB  = ws + o; o += (size_t)BB*TZ_*CH_;
  unsigned char* CHO = (unsigned char*)(ws + o); o += (size_t)BB*TZ_*64/4;

  float* Qb = BUF2;
  float* Kb = BUF2 + (size_t)BB*TT_*D_;
  float* Vb = BUF2 + (size_t)2*BB*TT_*D_;
  float* Yb = BUF2 + (size_t)3*BB*TT_*D_;

  k_pe   <<<dim3(TT_),    dim3(D_), 0, stream>>>(PE);
  k_embed<<<dim3(BB*TT_), dim3(D_), 0, stream>>>(text, emb, PE, H);

  const dim3 g44(D_/64, BB*TT_/64);
  for (int l=0;l<L_;l++){
    const float* wql = wq + (size_t)l*D_*D_;
    const float* wkl = wk + (size_t)l*D_*D_;
    const float* wvl = wv + (size_t)l*D_*D_;
    const float* wol = wo + (size_t)l*D_*D_;
    k_gemm<0><<<g44,256,0,stream>>>(H, D_, wql, D_, bq+l*D_, nullptr, 1, Qb, D_, D_);
    k_gemm<0><<<g44,256,0,stream>>>(H, D_, wkl, D_, bk+l*D_, nullptr, 1, Kb, D_, D_);
    k_gemm<0><<<g44,256,0,stream>>>(H, D_, wvl, D_, bv+l*D_, nullptr, 1, Vb, D_, D_);
    k_scores <<<dim3(TT_/64, TT_/64, BB*HEADS_),256,0,stream>>>(Qb, Kb, text, BIGS);
    k_softmax<<<dim3(BB*HEADS_*TT_),64,0,stream>>>(BIGS);
    k_av     <<<dim3(1, TT_/64, BB*HEADS_),256,0,stream>>>(BIGS, Vb, Yb);
    k_gemm<0><<<g44,256,0,stream>>>(Yb, D_, wol, D_, bo+l*D_, nullptr, 1, Qb, D_, D_);
    k_lnres  <<<dim3(BB*TT_),256,0,stream>>>(Qb, ln1g+l*D_, ln1b+l*D_, H);
    k_gemm<1><<<dim3(DFF_/64, BB*TT_/64),256,0,stream>>>(H, D_, w1+(size_t)l*D_*DFF_, DFF_, b1+l*DFF_, nullptr, 1, BUF1, DFF_, D_);
    k_gemm<0><<<g44,256,0,stream>>>(BUF1, DFF_, w2+(size_t)l*DFF_*D_, D_, b2+l*D_, nullptr, 1, Qb, D_, DFF_);
    k_lnres  <<<dim3(BB*TT_),256,0,stream>>>(Qb, ln2g+l*D_, ln2b+l*D_, H);
  }

  k_gemm<0><<<g44,256,0,stream>>>(H, D_, mu_w, D_, mu_b, nullptr, 1, MU,  D_, D_);
  k_gemm<0><<<g44,256,0,stream>>>(H, D_, lv_w, D_, lv_b, nullptr, 1, SPR, D_, D_);
  k_prep   <<<dim3(BB*TT_),256,0,stream>>>(MU, SPR, MSP, NC1, NC4);

  const float* zsrc = z;
  for (int f=0; f<FLOWS_; f++){
    k_condproj<<<dim3(BB),256,0,stream>>>(cond, f_cond + (size_t)f*G_*HID_, CONDP);
    k_gemm<0><<<dim3(HID_/64, BB*TZ_/64),256,0,stream>>>(
        zsrc, CH_, f_in + (size_t)f*(CH_/2)*HID_, HID_, f_in_b + f*HID_,
        CONDP, TZ_, BUF1, HID_, CH_/2);
    k_conv<<<dim3(HID_/64, TZ_/64, BB),256,0,stream>>>(
        BUF1, f_conv + (size_t)f*KCV*HID_*HID_, f_convb + f*HID_, BUF2);
    k_gemm<0><<<dim3((CH_/2)/64, BB*TZ_/64),256,0,stream>>>(
        BUF2, HID_, f_out + (size_t)f*HID_*(CH_/2), CH_/2, f_outb + f*(CH_/2),
        nullptr, 1, BUF1, CH_/2, HID_);
    float* zdst = (f & 1) ? ZCB : ZCA;
    k_flowmix<<<dim3((BB*TZ_*CH_)/256),256,0,stream>>>(zsrc, BUF1, zdst);
    zsrc = zdst;
  }

  k_logp<<<dim3(TT_/64, TZ_/64, BB),256,0,stream>>>(zsrc, MSP, SPR, NC1, NC4, text, BIGS);
  k_mas <<<dim3(BB),64,0,stream>>>(BIGS, text, CHO, PATH);
  k_gather<<<dim3((BB*TZ_*D_/4 + BB*TT_*D_/4)/256),256,0,stream>>>(MU, PATH, H, (float*)d_out);
}

// Round 3
// 3543.388 us; speedup vs baseline: 1.3808x; 1.3808x over previous
//
#include <hip/hip_runtime.h>

#define BB 16
#define TZ_ 2048
#define TT_ 512
#define D_ 256
#define DFF_ 1024
#define L_ 6
#define HEADS_ 4
#define DH_ 64
#define CH_ 256
#define HID_ 256
#define KCV 5
#define FLOWS_ 4
#define G_ 256
#define NEGF (-1000000000.0f)
#define LOG2PI 1.8378770664093453f

typedef unsigned short u16;
typedef __attribute__((ext_vector_type(8))) short short8v;
typedef __attribute__((ext_vector_type(4))) float f32x4;

__device__ __forceinline__ float wsum(float v){
#pragma unroll
  for (int o = 32; o; o >>= 1) v += __shfl_xor(v, o);
  return v;
}

__device__ __forceinline__ u16 f2bf(float x){
  unsigned u = __float_as_uint(x);
  return (u16)((u + 0x7FFFu + ((u >> 16) & 1u)) >> 16);
}
__device__ __forceinline__ float bf2f(u16 h){
  return __uint_as_float(((unsigned)h) << 16);
}

// ---------------- positional encoding (f64, matches np) ----------------
__global__ void k_pe(float* __restrict__ pe){
  int t = blockIdx.x, d = threadIdx.x;
  double e = (double)(2*(d>>1)) / (double)D_;
  double ang = (double)t * pow(10000.0, -e);
  pe[t*D_ + d] = (float)(((d&1)==0) ? sin(ang) : cos(ang));
}

// ---------------- embedding ----------------
__global__ void k_embed(const int* __restrict__ text, const float* __restrict__ emb,
                        const float* __restrict__ pe, float* __restrict__ h){
  int row = blockIdx.x, d = threadIdx.x;
  h[(size_t)row*D_ + d] = emb[(size_t)text[row]*D_ + d]*16.0f + pe[(row%TT_)*D_ + d];
}

// ---------------- generic tiled f32 GEMM (encoder) ----------------
template<int RELU>
__global__ __launch_bounds__(256,2) void k_gemm(
  const float* __restrict__ A, int lda,
  const float* __restrict__ W, int ldw,
  const float* __restrict__ bias,
  const float* __restrict__ bias2, int b2rows,
  float* __restrict__ C, int ldc, int K)
{
  __shared__ float As[16][64];
  __shared__ float Ws[16][64];
  const int t  = threadIdx.x;
  const int tx = t & 15, ty = t >> 4;
  const size_t row0 = (size_t)blockIdx.y * 64;
  const size_t col0 = (size_t)blockIdx.x * 64;
  const int arow = t >> 2, ak4 = (t & 3) << 2;
  const int wk = t >> 4, wc4 = (t & 15) << 2;
  float acc[4][4] = {};
  for (int k0 = 0; k0 < K; k0 += 16){
    __syncthreads();
    float4 av = *(const float4*)(A + (row0 + arow)*lda + k0 + ak4);
    As[ak4+0][arow]=av.x; As[ak4+1][arow]=av.y; As[ak4+2][arow]=av.z; As[ak4+3][arow]=av.w;
    *(float4*)&Ws[wk][wc4] = *(const float4*)(W + (size_t)(k0+wk)*ldw + col0 + wc4);
    __syncthreads();
#pragma unroll
    for (int kk=0;kk<16;kk++){
      float4 a4 = *(const float4*)&As[kk][ty<<2];
      float4 w4 = *(const float4*)&Ws[kk][tx<<2];
      float ar[4]={a4.x,a4.y,a4.z,a4.w}, wr[4]={w4.x,w4.y,w4.z,w4.w};
#pragma unroll
      for (int i=0;i<4;i++)
#pragma unroll
        for (int j=0;j<4;j++)
          acc[i][j] = fmaf(ar[i], wr[j], acc[i][j]);
    }
  }
#pragma unroll
  for (int i=0;i<4;i++){
    size_t r = row0 + (ty<<2) + i;
#pragma unroll
    for (int j=0;j<4;j++){
      size_t c = col0 + (tx<<2) + j;
      float v = acc[i][j];
      if (bias)  v += bias[c];
      if (bias2) v += bias2[(r / (size_t)b2rows)*ldc + c];
      if (RELU)  v = fmaxf(v, 0.0f);
      C[r*ldc + c] = v;
    }
  }
}

// ---------------- attention scores ----------------
__global__ __launch_bounds__(256,2) void k_scores(
  const float* __restrict__ q, const float* __restrict__ k,
  const int* __restrict__ text, float* __restrict__ S)
{
  const int bh = blockIdx.z, b = bh >> 2, h = bh & 3;
  const float* qb = q + (size_t)b*TT_*D_ + h*DH_;
  const float* kb = k + (size_t)b*TT_*D_ + h*DH_;
  __shared__ float Qs[16][64], Ks[16][64];
  const int t = threadIdx.x, tx = t&15, ty = t>>4;
  const int i0 = blockIdx.y*64, j0 = blockIdx.x*64;
  const int arow = t>>2, ak4 = (t&3)<<2;
  float acc[4][4] = {};
  for (int k0=0;k0<DH_;k0+=16){
    __syncthreads();
    float4 av = *(const float4*)(qb + (size_t)(i0+arow)*D_ + k0+ak4);
    Qs[ak4+0][arow]=av.x; Qs[ak4+1][arow]=av.y; Qs[ak4+2][arow]=av.z; Qs[ak4+3][arow]=av.w;
    float4 bv = *(const float4*)(kb + (size_t)(j0+arow)*D_ + k0+ak4);
    Ks[ak4+0][arow]=bv.x; Ks[ak4+1][arow]=bv.y; Ks[ak4+2][arow]=bv.z; Ks[ak4+3][arow]=bv.w;
    __syncthreads();
#pragma unroll
    for (int kk=0;kk<16;kk++){
      float4 a4 = *(const float4*)&Qs[kk][ty<<2];
      float4 w4 = *(const float4*)&Ks[kk][tx<<2];
      float ar[4]={a4.x,a4.y,a4.z,a4.w}, wr[4]={w4.x,w4.y,w4.z,w4.w};
#pragma unroll
      for (int i=0;i<4;i++)
#pragma unroll
        for (int j=0;j<4;j++) acc[i][j] = fmaf(ar[i], wr[j], acc[i][j]);
    }
  }
#pragma unroll
  for (int i=0;i<4;i++){
    int ii = i0 + (ty<<2) + i;
#pragma unroll
    for (int j=0;j<4;j++){
      int jj = j0 + (tx<<2) + j;
      float bias = (text[b*TT_ + jj] != 0) ? 0.0f : NEGF;
      S[((size_t)bh*TT_ + ii)*TT_ + jj] = acc[i][j]*0.125f + bias;
    }
  }
}

// ---------------- row softmax over 512 ----------------
__global__ __launch_bounds__(64) void k_softmax(float* __restrict__ S){
  size_t row = blockIdx.x;
  float* p = S + row*TT_;
  int ln = threadIdx.x;
  float4 a = *(float4*)(p + ln*8);
  float4 b = *(float4*)(p + ln*8 + 4);
  float x[8] = {a.x,a.y,a.z,a.w,b.x,b.y,b.z,b.w};
  float m = x[0];
#pragma unroll
  for (int i=1;i<8;i++) m = fmaxf(m, x[i]);
#pragma unroll
  for (int o2=32;o2;o2>>=1) m = fmaxf(m, __shfl_xor(m, o2));
  float s = 0.f;
#pragma unroll
  for (int i=0;i<8;i++){ x[i] = expf(x[i]-m); s += x[i]; }
  s = wsum(s);
  float inv = 1.0f/s;
  *(float4*)(p + ln*8)     = make_float4(x[0]*inv, x[1]*inv, x[2]*inv, x[3]*inv);
  *(float4*)(p + ln*8 + 4) = make_float4(x[4]*inv, x[5]*inv, x[6]*inv, x[7]*inv);
}

// ---------------- attn @ V ----------------
__global__ __launch_bounds__(256,2) void k_av(const float* __restrict__ P,
  const float* __restrict__ v, float* __restrict__ out){
  const int bh = blockIdx.z, b = bh >> 2, h = bh & 3;
  const float* Pb = P + (size_t)bh*TT_*TT_;
  const float* vb = v + (size_t)b*TT_*D_ + h*DH_;
  const int t = threadIdx.x, tx=t&15, ty=t>>4;
  const int i0 = blockIdx.y*64;
  const int arow=t>>2, ak4=(t&3)<<2, wk=t>>4, wc4=(t&15)<<2;
  __shared__ float As[16][64], Ws[16][64];
  float acc[4][4]={};
  for (int k0=0;k0<TT_;k0+=16){
    __syncthreads();
    float4 av = *(const float4*)(Pb + (size_t)(i0+arow)*TT_ + k0+ak4);
    As[ak4+0][arow]=av.x; As[ak4+1][arow]=av.y; As[ak4+2][arow]=av.z; As[ak4+3][arow]=av.w;
    *(float4*)&Ws[wk][wc4] = *(const float4*)(vb + (size_t)(k0+wk)*D_ + wc4);
    __syncthreads();
#pragma unroll
    for (int kk=0;kk<16;kk++){
      float4 a4 = *(const float4*)&As[kk][ty<<2];
      float4 w4 = *(const float4*)&Ws[kk][tx<<2];
      float ar[4]={a4.x,a4.y,a4.z,a4.w}, wr[4]={w4.x,w4.y,w4.z,w4.w};
#pragma unroll
      for (int i=0;i<4;i++)
#pragma unroll
        for (int j=0;j<4;j++) acc[i][j] = fmaf(ar[i], wr[j], acc[i][j]);
    }
  }
#pragma unroll
  for (int i=0;i<4;i++){
    size_t r = (size_t)b*TT_ + i0 + (ty<<2) + i;
#pragma unroll
    for (int j=0;j<4;j++)
      out[r*D_ + h*DH_ + (tx<<2) + j] = acc[i][j];
  }
}

// ---------------- residual + LayerNorm ----------------
__global__ __launch_bounds__(256) void k_lnres(const float* __restrict__ y,
  const float* __restrict__ g, const float* __restrict__ bb, float* __restrict__ h){
  size_t row = blockIdx.x; int d = threadIdx.x;
  float v = h[row*D_ + d] + y[row*D_ + d];
  float s = wsum(v), s2 = wsum(v*v);
  __shared__ float r1[4], r2[4];
  int w = d >> 6;
  if ((d & 63) == 0){ r1[w] = s; r2[w] = s2; }
  __syncthreads();
  s  = r1[0]+r1[1]+r1[2]+r1[3];
  s2 = r2[0]+r2[1]+r2[2]+r2[3];
  float mean = s * (1.0f/D_);
  float var  = s2 * (1.0f/D_) - mean*mean;
  float inv  = rsqrtf(var + 1e-6f);
  h[row*D_ + d] = g[d]*(v - mean)*inv + bb[d];
}

// ---------------- spr/msp/nc1/nc4 prep ----------------
__global__ __launch_bounds__(256) void k_prep(const float* __restrict__ mu, float* __restrict__ lv,
  float* __restrict__ msp, float* __restrict__ nc1, float* __restrict__ nc4){
  size_t row = blockIdx.x; int d = threadIdx.x;
  float l = lv[row*D_ + d];
  float m = mu[row*D_ + d];
  float sp = expf(-l);
  float s1 = wsum(l), s2 = wsum(m*m*sp);
  __shared__ float r1[4], r2[4];
  int w = d >> 6;
  if ((d&63)==0){ r1[w]=s1; r2[w]=s2; }
  __syncthreads();
  if (d == 0){
    nc1[row] = -0.5f*((float)D_*LOG2PI + (r1[0]+r1[1]+r1[2]+r1[3]));
    nc4[row] = -0.5f*(r2[0]+r2[1]+r2[2]+r2[3]);
  }
  lv[row*D_ + d]  = sp;
  msp[row*D_ + d] = m*sp;
}

// ---------------- cond @ flow_cond[f] ----------------
__global__ __launch_bounds__(256) void k_condproj(const float* __restrict__ cond,
  const float* __restrict__ W, float* __restrict__ out){
  const int b = blockIdx.x, n = threadIdx.x;
  float s = 0.f;
  for (int k2=0;k2<G_;k2++) s = fmaf(cond[b*G_ + k2], W[k2*HID_ + n], s);
  out[b*HID_ + n] = s;
}

// ================= split-bf16 (hi+lo) flow stack =================
// weights: WIT[n][k]=f_in[k][n]; WCT[o][w*256+k]; WOT[o][k]; each as hi+lo bf16 planes
__global__ void k_wprep2(const float* __restrict__ win, const float* __restrict__ wconv,
                         const float* __restrict__ wout,
                         u16* __restrict__ WITH, u16* __restrict__ WITL,
                         u16* __restrict__ WCTH, u16* __restrict__ WCTL,
                         u16* __restrict__ WOTH, u16* __restrict__ WOTL){
  int i = blockIdx.x*256 + threadIdx.x;
  float wv; u16 *dh, *dl; int idx;
  if (i < 32768){
    int n = i >> 7, k = i & 127;
    wv = win[k*256 + n]; dh = WITH; dl = WITL; idx = i;
  } else if (i < 32768 + 327680){
    int jj = i - 32768;
    int o = jj / 1280, r = jj - o*1280;
    wv = wconv[(size_t)r*256 + o]; dh = WCTH; dl = WCTL; idx = jj;
  } else {
    int jj = i - 360448;
    int o = jj >> 8, k = jj & 255;
    wv = wout[k*128 + o]; dh = WOTH; dl = WOTL; idx = jj;
  }
  u16 hh = f2bf(wv);
  dh[idx] = hh;
  dl[idx] = f2bf(wv - bf2f(hh));
}

// x0 (first 128 ch of zc) -> hi/lo bf16 planes [32768][128]
__global__ void k_x0prep2(const float* __restrict__ z, u16* __restrict__ xh, u16* __restrict__ xl){
  size_t i = ((size_t)blockIdx.x*256 + threadIdx.x) << 3;
  size_t m2 = i >> 7; int k = (int)(i & 127);
  const float* src = z + m2*256 + k;
  float4 a = *(const float4*)src; float4 b2 = *(const float4*)(src+4);
  float vv[8] = {a.x,a.y,a.z,a.w,b2.x,b2.y,b2.z,b2.w};
  short8v oh, ol;
#pragma unroll
  for (int r=0;r<8;r++){
    u16 hh = f2bf(vv[r]);
    oh[r] = (short)hh;
    ol[r] = (short)f2bf(vv[r] - bf2f(hh));
  }
  *(short8v*)(xh + i) = oh;
  *(short8v*)(xl + i) = ol;
}

// zero padded boundary rows of XpH/XpL (rows 0,1,2050,2051 per batch)
__global__ void k_padzero2(u16* __restrict__ XpH, u16* __restrict__ XpL){
  int i = blockIdx.x*256 + threadIdx.x;   // 32768 total
  u16* P = (i >> 14) ? XpL : XpH;
  int ii = i & 16383;
  int b = ii >> 10, rr = (ii >> 8) & 3, c = ii & 255;
  int row = (rr < 2) ? rr : (2048 + rr);
  P[((size_t)b*2052 + row)*256 + c] = 0;
}

// split-bf16 MFMA GEMM: C = epi(A @ Bt^T + bias (+cond)), A=Ah+Al, B=Bh+Bl.
// acc += Ah*Bh + Al*Bh + Ah*Bl   (Al*Bl ~2^-18, dropped)
// 128x128 tile, 4 waves, 16x16x32 bf16 MFMA, BK=32, XOR-swizzled LDS (2-way=free).
// padA/padC: padded-row remap row' = row + pad*(row>>11)  (conv time-padding).
template<int EPI, int SPLITOUT>   // EPI: 0 bias, 1 bias+cond, 2 tanh(acc+bias)
__global__ __launch_bounds__(256,2) void k_mf2(
  const u16* __restrict__ Ah, const u16* __restrict__ Al, int lda, int padA,
  const u16* __restrict__ Bh, const u16* __restrict__ Bl, int ldb,
  const float* __restrict__ bias, const float* __restrict__ cnd,
  void* __restrict__ CH, void* __restrict__ CL, int ldc, int padC, int K)
{
  __shared__ u16 AsmH[4096], AsmL[4096], BsmH[4096], BsmL[4096];
  char* AHB=(char*)AsmH; char* ALB=(char*)AsmL;
  char* BHB=(char*)BsmH; char* BLB=(char*)BsmL;
  const int t = threadIdx.x;
  const int m0 = blockIdx.y << 7, n0 = blockIdx.x << 7;
  const int w = t >> 6, l = t & 63;
  const int wr = (w >> 1) << 6, wc = (w & 1) << 6;
  const int lr = l & 15, lg = l >> 4;
  const int srow = t >> 1, sseg = t & 1;
  const int q = (srow >> 1) & 3;
  const int wo0 = srow*64 + ((((sseg<<1)|0) ^ q) << 4);
  const int wo1 = srow*64 + ((((sseg<<1)|1) ^ q) << 4);
  const int am = m0 + srow;
  const size_t aoff = (size_t)(am + padA*(am >> 11))*lda + (sseg << 4);
  const u16* AhP = Ah + aoff;
  const u16* AlP = Al + aoff;
  const size_t boff = (size_t)(n0 + srow)*ldb + (sseg << 4);
  const u16* BhP = Bh + boff;
  const u16* BlP = Bl + boff;
  const int qa = ((wr + lr) >> 1) & 3, qb = ((wc + lr) >> 1) & 3;
  const int raBase = (wr + lr)*64 + ((lg ^ qa) << 4);
  const int rbBase = (wc + lr)*64 + ((lg ^ qb) << 4);
  f32x4 acc[4][4];
#pragma unroll
  for (int i=0;i<4;i++)
#pragma unroll
    for (int j=0;j<4;j++) acc[i][j] = (f32x4){0.f,0.f,0.f,0.f};

  for (int k0 = 0; k0 < K; k0 += 32){
    float4 ah0 = *(const float4*)(AhP + k0);
    float4 ah1 = *(const float4*)(AhP + k0 + 8);
    float4 al0 = *(const float4*)(AlP + k0);
    float4 al1 = *(const float4*)(AlP + k0 + 8);
    float4 bh0 = *(const float4*)(BhP + k0);
    float4 bh1 = *(const float4*)(BhP + k0 + 8);
    float4 bl0 = *(const float4*)(BlP + k0);
    float4 bl1 = *(const float4*)(BlP + k0 + 8);
    __syncthreads();
    *(float4*)(AHB + wo0) = ah0;  *(float4*)(AHB + wo1) = ah1;
    *(float4*)(ALB + wo0) = al0;  *(float4*)(ALB + wo1) = al1;
    *(float4*)(BHB + wo0) = bh0;  *(float4*)(BHB + wo1) = bh1;
    *(float4*)(BLB + wo0) = bl0;  *(float4*)(BLB + wo1) = bl1;
    __syncthreads();
    short8v fah[4], fal[4], fbh[4], fbl[4];
#pragma unroll
    for (int i=0;i<4;i++){
      fah[i] = *(short8v*)(AHB + raBase + i*1024);
      fal[i] = *(short8v*)(ALB + raBase + i*1024);
    }
#pragma unroll
    for (int j=0;j<4;j++){
      fbh[j] = *(short8v*)(BHB + rbBase + j*1024);
      fbl[j] = *(short8v*)(BLB + rbBase + j*1024);
    }
#pragma unroll
    for (int i=0;i<4;i++)
#pragma unroll
      for (int j=0;j<4;j++){
        acc[i][j] = __builtin_amdgcn_mfma_f32_16x16x32_bf16(fah[i], fbh[j], acc[i][j], 0, 0, 0);
        acc[i][j] = __builtin_amdgcn_mfma_f32_16x16x32_bf16(fal[i], fbh[j], acc[i][j], 0, 0, 0);
        acc[i][j] = __builtin_amdgcn_mfma_f32_16x16x32_bf16(fah[i], fbl[j], acc[i][j], 0, 0, 0);
      }
  }

#pragma unroll
  for (int i=0;i<4;i++){
    int mbase = m0 + wr + i*16 + (lg << 2);
#pragma unroll
    for (int j=0;j<4;j++){
      int nn = n0 + wc + j*16 + lr;
      float bs = bias[nn];
      f32x4 v = acc[i][j];
#pragma unroll
      for (int r=0;r<4;r++){
        int m = mbase + r;
        float x = v[r] + bs;
        if (EPI == 1) x += cnd[((m >> 11) << 8) + nn];
        if (EPI == 2) x = tanhf(x);
        size_t ro = (size_t)(m + padC*(m >> 11))*ldc + nn;
        if (SPLITOUT){
          u16 xh = f2bf(x);
          ((u16*)CH)[ro] = xh;
          ((u16*)CL)[ro] = f2bf(x - bf2f(xh));
        } else {
          ((float*)CH)[ro] = x;
        }
      }
    }
  }
}

// ---------------- flow coupling recombine: dst = [x1 + m, x0] ----------------
__global__ void k_flowmix(const float* __restrict__ src, const float* __restrict__ m,
                          float* __restrict__ dst){
  size_t i = (size_t)blockIdx.x*256 + threadIdx.x;
  size_t row = i >> 8; int c = (int)(i & 255);
  float val;
  if (c < 128) val = src[row*CH_ + 128 + c] + m[row*(CH_/2) + c];
  else         val = src[row*CH_ + c - 128];
  dst[i] = val;
}

// ---------------- logp ----------------
__global__ __launch_bounds__(256,2) void k_logp(const float* __restrict__ zc,
  const float* __restrict__ msp, const float* __restrict__ spr,
  const float* __restrict__ nc1, const float* __restrict__ nc4,
  const int* __restrict__ text, float* __restrict__ lp){
  const int b = blockIdx.z, t0 = blockIdx.y*64, j0 = blockIdx.x*64;
  const int t = threadIdx.x, tx=t&15, ty=t>>4;
  const int arow=t>>2, ak4=(t&3)<<2;
  __shared__ float As[16][64], Ms[16][64], Ss[16][64];
  float acc[4][4]={};
  for (int k0=0;k0<D_;k0+=16){
    __syncthreads();
    float4 av = *(const float4*)(zc + ((size_t)b*TZ_ + t0+arow)*CH_ + k0+ak4);
    As[ak4+0][arow]=av.x; As[ak4+1][arow]=av.y; As[ak4+2][arow]=av.z; As[ak4+3][arow]=av.w;
    float4 mv = *(const float4*)(msp + ((size_t)b*TT_ + j0+arow)*D_ + k0+ak4);
    Ms[ak4+0][arow]=mv.x; Ms[ak4+1][arow]=mv.y; Ms[ak4+2][arow]=mv.z; Ms[ak4+3][arow]=mv.w;
    float4 sv = *(const float4*)(spr + ((size_t)b*TT_ + j0+arow)*D_ + k0+ak4);
    Ss[ak4+0][arow]=sv.x; Ss[ak4+1][arow]=sv.y; Ss[ak4+2][arow]=sv.z; Ss[ak4+3][arow]=sv.w;
    __syncthreads();
#pragma unroll
    for (int kk=0;kk<16;kk++){
      float4 a4 = *(const float4*)&As[kk][ty<<2];
      float4 m4 = *(const float4*)&Ms[kk][tx<<2];
      float4 s4 = *(const float4*)&Ss[kk][tx<<2];
      float ar[4]={a4.x,a4.y,a4.z,a4.w};
      float h2[4];
#pragma unroll
      for (int i=0;i<4;i++) h2[i] = -0.5f*ar[i]*ar[i];
      float mr[4]={m4.x,m4.y,m4.z,m4.w}, sr[4]={s4.x,s4.y,s4.z,s4.w};
#pragma unroll
      for (int i=0;i<4;i++)
#pragma unroll
        for (int j=0;j<4;j++)
          acc[i][j] = fmaf(ar[i], mr[j], fmaf(h2[i], sr[j], acc[i][j]));
    }
  }
#pragma unroll
  for (int j=0;j<4;j++){
    int jj = j0 + (tx<<2) + j;
    float base = nc1[b*TT_ + jj] + nc4[b*TT_ + jj];
    bool msk = (text[b*TT_ + jj] != 0);
#pragma unroll
    for (int i=0;i<4;i++){
      size_t r = (size_t)b*TZ_ + t0 + (ty<<2) + i;
      lp[r*TT_ + jj] = msk ? (acc[i][j] + base) : NEGF;
    }
  }
}

// ---------------- MAS with 16-deep register prefetch pipeline ----------------
#define PF_ 16
__global__ __launch_bounds__(64) void k_mas(const float* __restrict__ lp,
  const int* __restrict__ text, unsigned char* __restrict__ cho, int* __restrict__ path){
  const int b = blockIdx.x, ln = threadIdx.x;
  const float* L = lp + (size_t)b*TZ_*TT_;
  int cnt = 0;
#pragma unroll
  for (int i=0;i<8;i++) cnt += (text[b*TT_ + ln*8 + i] != 0) ? 1 : 0;
#pragma unroll
  for (int o2=32;o2;o2>>=1) cnt += __shfl_xor(cnt, o2);
  const int jlast = cnt - 1;
  float Q[8];
#pragma unroll
  for (int i=0;i<8;i++) Q[i] = NEGF;
  if (ln == 0) Q[0] = L[0];
  float4 P0[PF_], P1[PF_];
#pragma unroll
  for (int p=0;p<PF_;p++){
    const float* lt = L + (size_t)(1+p)*TT_ + ln*8;
    P0[p] = *(const float4*)lt;
    P1[p] = *(const float4*)(lt+4);
  }
  unsigned char* cb = cho + (size_t)b*TZ_*64;
  for (int t0=1; t0<TZ_; t0+=PF_){
#pragma unroll
    for (int p=0;p<PF_;p++){
      const int t2 = t0 + p;
      if (t2 < TZ_){
        float4 u0 = P0[p], u1 = P1[p];
        const int tn = t2 + PF_;
        if (tn < TZ_){
          const float* lt = L + (size_t)tn*TT_ + ln*8;
          P0[p] = *(const float4*)lt;
          P1[p] = *(const float4*)(lt+4);
        }
        float v[8] = {u0.x,u0.y,u0.z,u0.w,u1.x,u1.y,u1.z,u1.w};
        float qp = __shfl_up(Q[7], 1);
        if (ln == 0) qp = NEGF;
        unsigned bits = 0; float qs = qp;
#pragma unroll
        for (int i=0;i<8;i++){
          float old = Q[i];
          if (qs > old) bits |= (1u<<i);
          Q[i] = v[i] + fmaxf(old, qs);
          qs = old;
        }
        cb[(size_t)(t2-1)*64 + ln] = (unsigned char)bits;
      }
    }
  }
  __shared__ __align__(16) unsigned char lch[64*64];
  int j = jlast;
  if (ln == 0) path[b*TZ_ + TZ_-1] = j;
  __syncthreads();
  for (int tc = TZ_-1; tc >= 1; tc -= 64){
    int ns = min(64, tc);
#pragma unroll
    for (int p2=0;p2<4;p2++){
      int s = p2*16 + (ln>>2);
      if (s < ns){
        int c = (ln&3) << 4;
        *(float4*)&lch[s*64 + c] = *(const float4*)&cb[(size_t)(tc-1-s)*64 + c];
      }
    }
    __syncthreads();
    if (ln == 0){
      for (int s=0;s<ns;s++){
        int t2 = tc - s;
        unsigned bits = lch[s*64 + (j>>3)];
        j -= (int)((bits >> (j&7)) & 1u);
        path[b*TZ_ + t2 - 1] = j;
      }
    }
    __syncthreads();
  }
}

// ---------------- ctx gather + h copy ----------------
__global__ void k_gather(const float* __restrict__ mu, const int* __restrict__ path,
  const float* __restrict__ h, float* __restrict__ out){
  size_t i = (size_t)blockIdx.x*256 + threadIdx.x;
  const size_t N4 = (size_t)BB*TZ_*(D_/4);
  const size_t H4 = (size_t)BB*TT_*(D_/4);
  if (i < N4){
    size_t row = i >> 6; int c = (int)(i & 63);
    int b = (int)(row >> 11);
    int pj = path[row];
    ((float4*)out)[i] = *(const float4*)(mu + ((size_t)b*TT_ + pj)*D_ + (size_t)c*4);
  } else if (i < N4 + H4){
    size_t k2 = i - N4;
    ((float4*)out)[i] = ((const float4*)h)[k2];
  }
}

extern "C" void kernel_launch(void* const* d_in, const int* in_sizes, int n_in,
                              void* d_out, int out_size, void* d_ws, size_t ws_size,
                              hipStream_t stream)
{
  (void)in_sizes; (void)n_in; (void)out_size; (void)ws_size;
  const float* z      = (const float*)d_in[0];
  const int*   text   = (const int*)  d_in[1];
  const float* cond   = (const float*)d_in[2];
  const float* emb    = (const float*)d_in[3];
  const float* wq     = (const float*)d_in[4];
  const float* wk     = (const float*)d_in[5];
  const float* wv     = (const float*)d_in[6];
  const float* wo     = (const float*)d_in[7];
  const float* bq     = (const float*)d_in[8];
  const float* bk     = (const float*)d_in[9];
  const float* bv     = (const float*)d_in[10];
  const float* bo     = (const float*)d_in[11];
  const float* ln1g   = (const float*)d_in[12];
  const float* ln1b   = (const float*)d_in[13];
  const float* ln2g   = (const float*)d_in[14];
  const float* ln2b   = (const float*)d_in[15];
  const float* w1     = (const float*)d_in[16];
  const float* b1     = (const float*)d_in[17];
  const float* w2     = (const float*)d_in[18];
  const float* b2     = (const float*)d_in[19];
  const float* mu_w   = (const float*)d_in[20];
  const float* mu_b   = (const float*)d_in[21];
  const float* lv_w   = (const float*)d_in[22];
  const float* lv_b   = (const float*)d_in[23];
  const float* f_in   = (const float*)d_in[24];
  const float* f_in_b = (const float*)d_in[25];
  const float* f_cond = (const float*)d_in[26];
  const float* f_conv = (const float*)d_in[27];
  const float* f_convb= (const float*)d_in[28];
  const float* f_out  = (const float*)d_in[29];
  const float* f_outb = (const float*)d_in[30];

  float* ws = (float*)d_ws;
  size_t o = 0;
  float* PE   = ws + o; o += (size_t)TT_*D_;
  float* H    = ws + o; o += (size_t)BB*TT_*D_;
  float* MU   = ws + o; o += (size_t)BB*TT_*D_;
  float* SPR  = ws + o; o += (size_t)BB*TT_*D_;
  float* MSP  = ws + o; o += (size_t)BB*TT_*D_;
  float* NC1  = ws + o; o += (size_t)BB*TT_;
  float* NC4  = ws + o; o += (size_t)BB*TT_;
  float* CONDP= ws + o; o += (size_t)BB*HID_;
  int*   PATH = (int*)(ws + o); o += (size_t)BB*TZ_;
  float* BIGS = ws + o; o += (size_t)BB*HEADS_*TT_*TT_;  // scores/logp; flow arena start
  float* BUF1 = ws + o; o += (size_t)BB*TT_*DFF_;        // ffn tmp; flow arena
  float* BUF2 = ws + o; o += (size_t)BB*TZ_*HID_;        // q,k,v,y; flow arena
  float* ZCA  = ws + o; o += (size_t)BB*TZ_*CH_;
  float* ZCB  = ws + o; o += (size_t)BB*TZ_*CH_;
  unsigned char* CHO = (unsigned char*)(ws + o); o += (size_t)BB*TZ_*64/4;

  float* Qb = BUF2;
  float* Kb = BUF2 + (size_t)BB*TT_*D_;
  float* Vb = BUF2 + (size_t)2*BB*TT_*D_;
  float* Yb = BUF2 + (size_t)3*BB*TT_*D_;

  // split-bf16 flow arena spanning BIGS+BUF1+BUF2 (all free during flows; logp runs after)
  char* fb = (char*)BIGS;
  u16*  X0H = (u16*)(fb);                  //  8,388,608 B  [32768][128]
  u16*  X0L = (u16*)(fb + 8388608);        //  8,388,608 B
  u16*  XpH = (u16*)(fb + 16777216);       // 16,809,984 B  [16*2052][256]
  u16*  XpL = (u16*)(fb + 33587200);       // 16,809,984 B
  u16*  H2H = (u16*)(fb + 50397184);       // 16,777,216 B  [32768][256]
  u16*  H2L = (u16*)(fb + 67174400);       // 16,777,216 B
  float* MB = (float*)(fb + 83951616);     // 16,777,216 B  [32768][128] f32
  u16*  WITH = (u16*)(fb + 100728832);     // weights hi/lo
  u16*  WITL = WITH + 32768;
  u16*  WCTH = WITL + 32768;
  u16*  WCTL = WCTH + 327680;
  u16*  WOTH = WCTL + 327680;
  u16*  WOTL = WOTH + 32768;               // ends at 102,301,696 B < 134,217,728 B

  k_pe   <<<dim3(TT_),    dim3(D_), 0, stream>>>(PE);
  k_embed<<<dim3(BB*TT_), dim3(D_), 0, stream>>>(text, emb, PE, H);

  const dim3 g44(D_/64, BB*TT_/64);
  for (int l=0;l<L_;l++){
    const float* wql = wq + (size_t)l*D_*D_;
    const float* wkl = wk + (size_t)l*D_*D_;
    const float* wvl = wv + (size_t)l*D_*D_;
    const float* wol = wo + (size_t)l*D_*D_;
    k_gemm<0><<<g44,256,0,stream>>>(H, D_, wql, D_, bq+l*D_, nullptr, 1, Qb, D_, D_);
    k_gemm<0><<<g44,256,0,stream>>>(H, D_, wkl, D_, bk+l*D_, nullptr, 1, Kb, D_, D_);
    k_gemm<0><<<g44,256,0,stream>>>(H, D_, wvl, D_, bv+l*D_, nullptr, 1, Vb, D_, D_);
    k_scores <<<dim3(TT_/64, TT_/64, BB*HEADS_),256,0,stream>>>(Qb, Kb, text, BIGS);
    k_softmax<<<dim3(BB*HEADS_*TT_),64,0,stream>>>(BIGS);
    k_av     <<<dim3(1, TT_/64, BB*HEADS_),256,0,stream>>>(BIGS, Vb, Yb);
    k_gemm<0><<<g44,256,0,stream>>>(Yb, D_, wol, D_, bo+l*D_, nullptr, 1, Qb, D_, D_);
    k_lnres  <<<dim3(BB*TT_),256,0,stream>>>(Qb, ln1g+l*D_, ln1b+l*D_, H);
    k_gemm<1><<<dim3(DFF_/64, BB*TT_/64),256,0,stream>>>(H, D_, w1+(size_t)l*D_*DFF_, DFF_, b1+l*DFF_, nullptr, 1, BUF1, DFF_, D_);
    k_gemm<0><<<g44,256,0,stream>>>(BUF1, DFF_, w2+(size_t)l*DFF_*D_, D_, b2+l*D_, nullptr, 1, Qb, D_, DFF_);
    k_lnres  <<<dim3(BB*TT_),256,0,stream>>>(Qb, ln2g+l*D_, ln2b+l*D_, H);
  }

  k_gemm<0><<<g44,256,0,stream>>>(H, D_, mu_w, D_, mu_b, nullptr, 1, MU,  D_, D_);
  k_gemm<0><<<g44,256,0,stream>>>(H, D_, lv_w, D_, lv_b, nullptr, 1, SPR, D_, D_);
  k_prep   <<<dim3(BB*TT_),256,0,stream>>>(MU, SPR, MSP, NC1, NC4);

  // ---- flows (split-bf16 MFMA) ----
  k_padzero2<<<dim3(128),256,0,stream>>>(XpH, XpL);
  const float* zsrc = z;
  for (int f=0; f<FLOWS_; f++){
    k_condproj<<<dim3(BB),256,0,stream>>>(cond, f_cond + (size_t)f*G_*HID_, CONDP);
    k_wprep2<<<dim3(1536),256,0,stream>>>(f_in + (size_t)f*(CH_/2)*HID_,
                                          f_conv + (size_t)f*KCV*HID_*HID_,
                                          f_out + (size_t)f*HID_*(CH_/2),
                                          WITH, WITL, WCTH, WCTL, WOTH, WOTL);
    k_x0prep2<<<dim3(2048),256,0,stream>>>(zsrc, X0H, X0L);
    // hh1 = x0 @ Win + b + cond  -> split bf16 into padded Xp (interior at +2 rows)
    k_mf2<1,1><<<dim3(2,256),256,0,stream>>>(X0H, X0L, 128, 0, WITH, WITL, 128,
        f_in_b + f*HID_, CONDP, (void*)(XpH + 512), (void*)(XpL + 512), 256, 4, 128);
    // hh2 = tanh(conv(hh1) + bc)  (K = 5*256 = 1280 over padded window)
    k_mf2<2,1><<<dim3(2,256),256,0,stream>>>(XpH, XpL, 256, 4, WCTH, WCTL, 1280,
        f_convb + f*HID_, nullptr, (void*)H2H, (void*)H2L, 256, 0, 1280);
    // m = hh2 @ Wout + b  (f32 out)
    k_mf2<0,0><<<dim3(1,256),256,0,stream>>>(H2H, H2L, 256, 0, WOTH, WOTL, 256,
        f_outb + f*(CH_/2), nullptr, (void*)MB, nullptr, 128, 0, 256);
    float* zdst = (f & 1) ? ZCB : ZCA;
    k_flowmix<<<dim3((BB*TZ_*CH_)/256),256,0,stream>>>(zsrc, MB, zdst);
    zsrc = zdst;
  }

  k_logp<<<dim3(TT_/64, TZ_/64, BB),256,0,stream>>>(zsrc, MSP, SPR, NC1, NC4, text, BIGS);
  k_mas <<<dim3(BB),64,0,stream>>>(BIGS, text, CHO, PATH);
  k_gather<<<dim3((BB*TZ_*D_/4 + BB*TT_*D_/4)/256),256,0,stream>>>(MU, PATH, H, (float*)d_out);
}

// Round 5
// 2482.633 us; speedup vs baseline: 1.9708x; 1.4273x over previous
//
#include <hip/hip_runtime.h>

#define BB 16
#define TZ_ 2048
#define TT_ 512
#define D_ 256
#define DFF_ 1024
#define L_ 6
#define HEADS_ 4
#define DH_ 64
#define CH_ 256
#define HID_ 256
#define KCV 5
#define FLOWS_ 4
#define G_ 256
#define NEGF (-1000000000.0f)
#define LOG2PI 1.8378770664093453f

typedef unsigned short u16;
typedef __attribute__((ext_vector_type(8))) short short8v;
typedef __attribute__((ext_vector_type(4))) float f32x4;

__device__ __forceinline__ float wsum(float v){
#pragma unroll
  for (int o = 32; o; o >>= 1) v += __shfl_xor(v, o);
  return v;
}
__device__ __forceinline__ u16 f2bf(float x){
  unsigned u = __float_as_uint(x);
  return (u16)((u + 0x7FFFu + ((u >> 16) & 1u)) >> 16);
}
__device__ __forceinline__ float bf2f(u16 h){
  return __uint_as_float(((unsigned)h) << 16);
}
__device__ __forceinline__ unsigned pk2f(float a, float b){
  return __builtin_amdgcn_perm(__float_as_uint(b), __float_as_uint(a), 0x07060302u);
}
__device__ __forceinline__ float trnc(float f){
  return __uint_as_float(__float_as_uint(f) & 0xFFFF0000u);
}
__device__ __forceinline__ void cvt8t(float4 x, float4 y, uint4 &hi, uint4 &lo){
  hi.x = pk2f(x.x, x.y); hi.y = pk2f(x.z, x.w);
  hi.z = pk2f(y.x, y.y); hi.w = pk2f(y.z, y.w);
  float r0 = x.x - trnc(x.x), r1 = x.y - trnc(x.y), r2 = x.z - trnc(x.z), r3 = x.w - trnc(x.w);
  float r4 = y.x - trnc(y.x), r5 = y.y - trnc(y.y), r6 = y.z - trnc(y.z), r7 = y.w - trnc(y.w);
  lo.x = pk2f(r0, r1); lo.y = pk2f(r2, r3); lo.z = pk2f(r4, r5); lo.w = pk2f(r6, r7);
}
__device__ __forceinline__ unsigned rneh(float f){
  unsigned v = __float_as_uint(f);
  return (v + 0x7FFFu + ((v >> 16) & 1u)) & 0xFFFF0000u;
}
__device__ __forceinline__ void cvt8r(float4 x, float4 y, uint4 &hi, uint4 &lo){
  unsigned h0=rneh(x.x), h1=rneh(x.y), h2=rneh(x.z), h3=rneh(x.w);
  unsigned h4=rneh(y.x), h5=rneh(y.y), h6=rneh(y.z), h7=rneh(y.w);
  hi.x = h1 | (h0>>16); hi.y = h3 | (h2>>16); hi.z = h5 | (h4>>16); hi.w = h7 | (h6>>16);
  float r0 = x.x - __uint_as_float(h0), r1 = x.y - __uint_as_float(h1);
  float r2 = x.z - __uint_as_float(h2), r3 = x.w - __uint_as_float(h3);
  float r4 = y.x - __uint_as_float(h4), r5 = y.y - __uint_as_float(h5);
  float r6 = y.z - __uint_as_float(h6), r7 = y.w - __uint_as_float(h7);
  lo.x = pk2f(r0, r1); lo.y = pk2f(r2, r3); lo.z = pk2f(r4, r5); lo.w = pk2f(r6, r7);
}

// ---------------- positional encoding ----------------
__global__ void k_pe(float* __restrict__ pe){
  int t = blockIdx.x, d = threadIdx.x;
  double e = (double)(2*(d>>1)) / (double)D_;
  double ang = (double)t * pow(10000.0, -e);
  pe[t*D_ + d] = (float)(((d&1)==0) ? sin(ang) : cos(ang));
}
// ---------------- embedding ----------------
__global__ void k_embed(const int* __restrict__ text, const float* __restrict__ emb,
                        const float* __restrict__ pe, float* __restrict__ h){
  int row = blockIdx.x, d = threadIdx.x;
  h[(size_t)row*D_ + d] = emb[(size_t)text[row]*D_ + d]*16.0f + pe[(row%TT_)*D_ + d];
}

// ---------------- weight transposes (74 slots of 256x256) ----------------
__global__ __launch_bounds__(256) void k_wt(
  const float* __restrict__ wq, const float* __restrict__ wk,
  const float* __restrict__ wv, const float* __restrict__ wo,
  const float* __restrict__ mu_w, const float* __restrict__ lv_w,
  const float* __restrict__ w1, const float* __restrict__ w2,
  float* __restrict__ QKVT, float* __restrict__ OT, float* __restrict__ MULVT,
  float* __restrict__ W1T, float* __restrict__ W2T)
{
  __shared__ float td[64][65];
  const int s = blockIdx.y, tile = blockIdx.x, t = threadIdx.x;
  const float* inb; float* outb; int istride, ostride;
  if (s < 24){
    int l = s>>2, wsel = s&3;
    const float* w = (wsel==0?wq:wsel==1?wk:wsel==2?wv:wo);
    inb = w + (size_t)l*65536; istride = 256;
    if (wsel < 3) outb = QKVT + (size_t)l*196608 + wsel*65536;
    else          outb = OT   + (size_t)l*65536;
    ostride = 256;
  } else if (s < 26){
    inb = (s==24 ? mu_w : lv_w); istride = 256;
    outb = MULVT + (size_t)(s-24)*65536; ostride = 256;
  } else if (s < 50){
    int idx = s-26, l = idx>>2, b2 = idx&3;
    inb = w1 + (size_t)l*262144 + b2*256; istride = 1024;
    outb = W1T + (size_t)l*262144 + (size_t)b2*65536; ostride = 256;
  } else {
    int idx = s-50, l = idx>>2, b2 = idx&3;
    inb = w2 + (size_t)l*262144 + (size_t)b2*65536; istride = 256;
    outb = W2T + (size_t)l*262144 + b2*256; ostride = 1024;
  }
  const int kt = (tile>>2)*64, nt = (tile&3)*64;
  const int r = t>>2, cq = (t&3)*16;
#pragma unroll
  for (int c=0;c<16;c+=4){
    float4 v = *(const float4*)(inb + (size_t)(kt + r)*istride + nt + cq + c);
    td[r][cq+c+0]=v.x; td[r][cq+c+1]=v.y; td[r][cq+c+2]=v.z; td[r][cq+c+3]=v.w;
  }
  __syncthreads();
#pragma unroll
  for (int c=0;c<16;c+=4){
    float4 v = make_float4(td[cq+c+0][r], td[cq+c+1][r], td[cq+c+2][r], td[cq+c+3][r]);
    *(float4*)(outb + (size_t)(nt + r)*ostride + kt + cq + c) = v;
  }
}

// ---------------- V transpose per layer: VT[b][dfull][j] ----------------
__global__ __launch_bounds__(256) void k_vt(const float* __restrict__ QKV, float* __restrict__ VT){
  __shared__ float td[64][65];
  const int b = blockIdx.z, dt = blockIdx.x, jt = blockIdx.y, t = threadIdx.x;
  const float* inb = QKV + (size_t)b*512*768 + 512;
  float* outb = VT + (size_t)b*131072;
  const int r = t>>2, cq = (t&3)*16;
#pragma unroll
  for (int c=0;c<16;c+=4){
    float4 v = *(const float4*)(inb + (size_t)(jt*64 + r)*768 + dt*64 + cq + c);
    td[r][cq+c+0]=v.x; td[r][cq+c+1]=v.y; td[r][cq+c+2]=v.z; td[r][cq+c+3]=v.w;
  }
  __syncthreads();
#pragma unroll
  for (int c=0;c<16;c+=4){
    float4 v = make_float4(td[cq+c+0][r], td[cq+c+1][r], td[cq+c+2][r], td[cq+c+3][r]);
    *(float4*)(outb + (size_t)(dt*64 + r)*512 + jt*64 + cq + c) = v;
  }
}

// ---------------- bias concat ----------------
__global__ void k_bcat(const float* __restrict__ bq, const float* __restrict__ bk,
                       const float* __restrict__ bv, const float* __restrict__ mu_b,
                       const float* __restrict__ lv_b,
                       float* __restrict__ BQKV, float* __restrict__ MULVB){
  int i = blockIdx.x*256 + threadIdx.x;
  if (i < 4608){
    int l = i/768, c = i%768;
    float v = c<256 ? bq[l*256+c] : (c<512 ? bk[l*256+c-256] : bv[l*256+c-512]);
    BQKV[i] = v;
  } else if (i < 5120){
    int c = i-4608;
    MULVB[c] = c<256 ? mu_b[c] : lv_b[c-256];
  }
}

// =========== universal split-bf16 MFMA GEMM ===========
// EPI: 0 +bias, 1 relu(+bias), 2 scores (*0.125 + mask), 3 logp (+nc1+nc4, mask)
// AM: 0 f32 trunc-split, 1 presplit u16, 2 [zc|-0.5zc^2] virtual concat (rne split)
template<int WN, int EPI, int AM, int BMD>
__global__ __launch_bounds__(256,2) void k_mg(
  const void* __restrict__ Ap, const void* __restrict__ ApL, int lda, int azhi, int azlo,
  const void* __restrict__ Bp, const void* __restrict__ BpL, int ldb, int bzhi, int bzlo,
  const float* __restrict__ bias, const int* __restrict__ text,
  const float* __restrict__ nc1v, const float* __restrict__ nc4v,
  float* __restrict__ C, int ldc, int czhi, int czlo, int K)
{
  constexpr int BN = WN*32;
  __shared__ u16 AH[4096], AL[4096];
  __shared__ u16 BH[BN*32], BL[BN*32];
  char* AHB=(char*)AH; char* ALB=(char*)AL; char* BHB=(char*)BH; char* BLB=(char*)BL;
  const int t = threadIdx.x, z = blockIdx.z;
  const int m0 = blockIdx.y*128, n0 = blockIdx.x*BN;
  const size_t aoff = (size_t)(z>>2)*azhi + (size_t)(z&3)*azlo;
  const size_t boff = (size_t)(z>>2)*bzhi + (size_t)(z&3)*bzlo;
  const size_t coff = (size_t)(z>>2)*czhi + (size_t)(z&3)*czlo;
  const int w = t>>6, l = t&63;
  const int wr = (w>>1)*64, wc = (w&1)*(WN*16);
  const int lr = l&15, lg = l>>4;
  const int srow = t>>1, sseg = t&1;
  const int q  = (srow>>1)&3;
  const int wo0 = srow*64 + ((((sseg<<1)|0)^q)<<4);
  const int wo1 = srow*64 + ((((sseg<<1)|1)^q)<<4);
  const bool bact = (WN==4) || (t < 128);
  const int qa = ((wr+lr)>>1)&3, qb2 = ((wc+lr)>>1)&3;
  const int raBase = (wr+lr)*64 + ((lg^qa)<<4);
  const int rbBase = (wc+lr)*64 + ((lg^qb2)<<4);

  const float* Af = nullptr; const u16* AfH = nullptr; const u16* AfL = nullptr;
  if constexpr (AM==0 || AM==2){ Af = (const float*)Ap + aoff; }
  else { AfH = (const u16*)Ap + aoff; AfL = (const u16*)ApL + aoff; }
  const float* Bf = nullptr; const u16* BfH = nullptr; const u16* BfL = nullptr;
  if constexpr (BMD==0){ Bf = (const float*)Bp + boff; }
  else { BfH = (const u16*)Bp + boff; BfL = (const u16*)BpL + boff; }

  f32x4 acc[4][WN];
#pragma unroll
  for (int i=0;i<4;i++)
#pragma unroll
    for (int j=0;j<WN;j++) acc[i][j] = (f32x4){0.f,0.f,0.f,0.f};

  for (int k0 = 0; k0 < K; k0 += 32){
    uint4 ahi0, ahi1, alo0, alo1;
    if constexpr (AM==0){
      const float* p = Af + (size_t)(m0+srow)*lda + k0 + sseg*16;
      float4 a0=*(const float4*)p, a1=*(const float4*)(p+4);
      float4 a2=*(const float4*)(p+8), a3=*(const float4*)(p+12);
      cvt8t(a0,a1,ahi0,alo0); cvt8t(a2,a3,ahi1,alo1);
    } else if constexpr (AM==1){
      const u16* ph = AfH + (size_t)(m0+srow)*lda + k0 + sseg*16;
      const u16* pl = AfL + (size_t)(m0+srow)*lda + k0 + sseg*16;
      ahi0 = *(const uint4*)ph; ahi1 = *(const uint4*)(ph+8);
      alo0 = *(const uint4*)pl; alo1 = *(const uint4*)(pl+8);
    } else {
      int kg = k0 + sseg*16;
      const float* p = Af + (size_t)(m0+srow)*lda + (kg < 256 ? kg : kg - 256);
      float4 a0=*(const float4*)p, a1=*(const float4*)(p+4);
      float4 a2=*(const float4*)(p+8), a3=*(const float4*)(p+12);
      if (kg >= 256){
        a0.x=-0.5f*a0.x*a0.x; a0.y=-0.5f*a0.y*a0.y; a0.z=-0.5f*a0.z*a0.z; a0.w=-0.5f*a0.w*a0.w;
        a1.x=-0.5f*a1.x*a1.x; a1.y=-0.5f*a1.y*a1.y; a1.z=-0.5f*a1.z*a1.z; a1.w=-0.5f*a1.w*a1.w;
        a2.x=-0.5f*a2.x*a2.x; a2.y=-0.5f*a2.y*a2.y; a2.z=-0.5f*a2.z*a2.z; a2.w=-0.5f*a2.w*a2.w;
        a3.x=-0.5f*a3.x*a3.x; a3.y=-0.5f*a3.y*a3.y; a3.z=-0.5f*a3.z*a3.z; a3.w=-0.5f*a3.w*a3.w;
      }
      cvt8r(a0,a1,ahi0,alo0); cvt8r(a2,a3,ahi1,alo1);
    }
    uint4 bhi0, bhi1, blo0, blo1;
    if (bact){
      if constexpr (BMD==0){
        const float* p = Bf + (size_t)(n0+srow)*ldb + k0 + sseg*16;
        float4 b0=*(const float4*)p, b1=*(const float4*)(p+4);
        float4 b2=*(const float4*)(p+8), b3=*(const float4*)(p+12);
        cvt8t(b0,b1,bhi0,blo0); cvt8t(b2,b3,bhi1,blo1);
      } else {
        const u16* ph = BfH + (size_t)(n0+srow)*ldb + k0 + sseg*16;
        const u16* pl = BfL + (size_t)(n0+srow)*ldb + k0 + sseg*16;
        bhi0 = *(const uint4*)ph; bhi1 = *(const uint4*)(ph+8);
        blo0 = *(const uint4*)pl; blo1 = *(const uint4*)(pl+8);
      }
    }
    __syncthreads();
    *(uint4*)(AHB + wo0) = ahi0;  *(uint4*)(AHB + wo1) = ahi1;
    *(uint4*)(ALB + wo0) = alo0;  *(uint4*)(ALB + wo1) = alo1;
    if (bact){
      *(uint4*)(BHB + wo0) = bhi0;  *(uint4*)(BHB + wo1) = bhi1;
      *(uint4*)(BLB + wo0) = blo0;  *(uint4*)(BLB + wo1) = blo1;
    }
    __syncthreads();
    short8v fah[4], fal[4], fbh[WN], fbl[WN];
#pragma unroll
    for (int i=0;i<4;i++){
      fah[i] = *(short8v*)(AHB + raBase + i*1024);
      fal[i] = *(short8v*)(ALB + raBase + i*1024);
    }
#pragma unroll
    for (int j=0;j<WN;j++){
      fbh[j] = *(short8v*)(BHB + rbBase + j*1024);
      fbl[j] = *(short8v*)(BLB + rbBase + j*1024);
    }
#pragma unroll
    for (int i=0;i<4;i++)
#pragma unroll
      for (int j=0;j<WN;j++){
        acc[i][j] = __builtin_amdgcn_mfma_f32_16x16x32_bf16(fah[i], fbh[j], acc[i][j], 0,0,0);
        acc[i][j] = __builtin_amdgcn_mfma_f32_16x16x32_bf16(fal[i], fbh[j], acc[i][j], 0,0,0);
        acc[i][j] = __builtin_amdgcn_mfma_f32_16x16x32_bf16(fah[i], fbl[j], acc[i][j], 0,0,0);
      }
  }

#pragma unroll
  for (int i=0;i<4;i++){
    int mm0 = m0 + wr + i*16 + (lg<<2);
#pragma unroll
    for (int j=0;j<WN;j++){
      int nn = n0 + wc + j*16 + lr;
      float bs = 0.f; float ncb = 0.f; bool msk = true;
      if (EPI==0 || EPI==1) bs = bias ? bias[nn] : 0.f;
      if (EPI==2) msk = (text[(z>>2)*TT_ + nn] != 0);
      if (EPI==3){ ncb = nc1v[z*TT_+nn] + nc4v[z*TT_+nn]; msk = (text[z*TT_+nn] != 0); }
      f32x4 v = acc[i][j];
#pragma unroll
      for (int r=0;r<4;r++){
        int m = mm0 + r;
        float x;
        if (EPI==0)      x = v[r] + bs;
        else if (EPI==1) x = fmaxf(v[r] + bs, 0.f);
        else if (EPI==2) x = v[r]*0.125f + (msk ? 0.f : NEGF);
        else             x = msk ? (v[r] + ncb) : NEGF;
        C[coff + (size_t)m*ldc + nn] = x;
      }
    }
  }
}

// ---------------- row softmax over 512 ----------------
__global__ __launch_bounds__(64) void k_softmax(float* __restrict__ S){
  size_t row = blockIdx.x;
  float* p = S + row*TT_;
  int ln = threadIdx.x;
  float4 a = *(float4*)(p + ln*8);
  float4 b = *(float4*)(p + ln*8 + 4);
  float x[8] = {a.x,a.y,a.z,a.w,b.x,b.y,b.z,b.w};
  float m = x[0];
#pragma unroll
  for (int i=1;i<8;i++) m = fmaxf(m, x[i]);
#pragma unroll
  for (int o2=32;o2;o2>>=1) m = fmaxf(m, __shfl_xor(m, o2));
  float s = 0.f;
#pragma unroll
  for (int i=0;i<8;i++){ x[i] = expf(x[i]-m); s += x[i]; }
  s = wsum(s);
  float inv = 1.0f/s;
  *(float4*)(p + ln*8)     = make_float4(x[0]*inv, x[1]*inv, x[2]*inv, x[3]*inv);
  *(float4*)(p + ln*8 + 4) = make_float4(x[4]*inv, x[5]*inv, x[6]*inv, x[7]*inv);
}

// ---------------- residual + LayerNorm ----------------
__global__ __launch_bounds__(256) void k_lnres(const float* __restrict__ y,
  const float* __restrict__ g, const float* __restrict__ bb, float* __restrict__ h){
  size_t row = blockIdx.x; int d = threadIdx.x;
  float v = h[row*D_ + d] + y[row*D_ + d];
  float s = wsum(v), s2 = wsum(v*v);
  __shared__ float r1[4], r2[4];
  int w = d >> 6;
  if ((d & 63) == 0){ r1[w] = s; r2[w] = s2; }
  __syncthreads();
  s  = r1[0]+r1[1]+r1[2]+r1[3];
  s2 = r2[0]+r2[1]+r2[2]+r2[3];
  float mean = s * (1.0f/D_);
  float var  = s2 * (1.0f/D_) - mean*mean;
  float inv  = rsqrtf(var + 1e-6f);
  h[row*D_ + d] = g[d]*(v - mean)*inv + bb[d];
}

// ---------------- prep: nc1/nc4 + B2 split planes [msp | spr] ----------------
__global__ __launch_bounds__(256) void k_prep(const float* __restrict__ mulv,
  u16* __restrict__ b2h, u16* __restrict__ b2l,
  float* __restrict__ nc1, float* __restrict__ nc4){
  size_t row = blockIdx.x; int d = threadIdx.x;
  float m = mulv[row*512 + d];
  float lv = mulv[row*512 + 256 + d];
  float sp = expf(-lv);
  float ms = m*sp;
  float s1 = wsum(lv), s2 = wsum(m*ms);
  __shared__ float r1[4], r2[4];
  int w = d >> 6;
  if ((d&63)==0){ r1[w]=s1; r2[w]=s2; }
  __syncthreads();
  if (d == 0){
    nc1[row] = -0.5f*((float)D_*LOG2PI + (r1[0]+r1[1]+r1[2]+r1[3]));
    nc4[row] = -0.5f*(r2[0]+r2[1]+r2[2]+r2[3]);
  }
  unsigned hm = rneh(ms);
  b2h[row*512 + d] = (u16)(hm>>16);
  b2l[row*512 + d] = f2bf(ms - __uint_as_float(hm));
  unsigned hs = rneh(sp);
  b2h[row*512 + 256 + d] = (u16)(hs>>16);
  b2l[row*512 + 256 + d] = f2bf(sp - __uint_as_float(hs));
}

// ---------------- cond @ flow_cond[f] ----------------
__global__ __launch_bounds__(256) void k_condproj(const float* __restrict__ cond,
  const float* __restrict__ W, float* __restrict__ out){
  const int b = blockIdx.x, n = threadIdx.x;
  float s = 0.f;
  for (int k2=0;k2<G_;k2++) s = fmaf(cond[b*G_ + k2], W[k2*HID_ + n], s);
  out[b*HID_ + n] = s;
}

// ================= split-bf16 flow stack (validated round 3) =================
__global__ void k_wprep2(const float* __restrict__ win, const float* __restrict__ wconv,
                         const float* __restrict__ wout,
                         u16* __restrict__ WITH, u16* __restrict__ WITL,
                         u16* __restrict__ WCTH, u16* __restrict__ WCTL,
                         u16* __restrict__ WOTH, u16* __restrict__ WOTL){
  int i = blockIdx.x*256 + threadIdx.x;
  float wv2; u16 *dh, *dl; int idx;
  if (i < 32768){
    int n = i >> 7, k = i & 127;
    wv2 = win[k*256 + n]; dh = WITH; dl = WITL; idx = i;
  } else if (i < 32768 + 327680){
    int jj = i - 32768;
    int o = jj / 1280, r = jj - o*1280;
    wv2 = wconv[(size_t)r*256 + o]; dh = WCTH; dl = WCTL; idx = jj;
  } else {
    int jj = i - 360448;
    int o = jj >> 8, k = jj & 255;
    wv2 = wout[k*128 + o]; dh = WOTH; dl = WOTL; idx = jj;
  }
  u16 hh = f2bf(wv2);
  dh[idx] = hh;
  dl[idx] = f2bf(wv2 - bf2f(hh));
}

__global__ void k_x0prep2(const float* __restrict__ z, u16* __restrict__ xh, u16* __restrict__ xl){
  size_t i = ((size_t)blockIdx.x*256 + threadIdx.x) << 3;
  size_t m2 = i >> 7; int k = (int)(i & 127);
  const float* src = z + m2*256 + k;
  float4 a = *(const float4*)src; float4 b2 = *(const float4*)(src+4);
  float vv[8] = {a.x,a.y,a.z,a.w,b2.x,b2.y,b2.z,b2.w};
  short8v oh, ol;
#pragma unroll
  for (int r=0;r<8;r++){
    u16 hh = f2bf(vv[r]);
    oh[r] = (short)hh;
    ol[r] = (short)f2bf(vv[r] - bf2f(hh));
  }
  *(short8v*)(xh + i) = oh;
  *(short8v*)(xl + i) = ol;
}

__global__ void k_padzero2(u16* __restrict__ XpH, u16* __restrict__ XpL){
  int i = blockIdx.x*256 + threadIdx.x;
  u16* P = (i >> 14) ? XpL : XpH;
  int ii = i & 16383;
  int b = ii >> 10, rr = (ii >> 8) & 3, c = ii & 255;
  int row = (rr < 2) ? rr : (2048 + rr);
  P[((size_t)b*2052 + row)*256 + c] = 0;
}

// EPI: 0 bias, 1 bias+cond, 2 tanh(acc+bias), 3 m+x1 fused flowmix (cnd = zsrc)
template<int EPI, int SPLITOUT>
__global__ __launch_bounds__(256,2) void k_mf2(
  const u16* __restrict__ Ah, const u16* __restrict__ Al, int lda, int padA,
  const u16* __restrict__ Bh, const u16* __restrict__ Bl, int ldb,
  const float* __restrict__ bias, const float* __restrict__ cnd,
  void* __restrict__ CH, void* __restrict__ CL, int ldc, int padC, int K)
{
  __shared__ u16 AsmH[4096], AsmL[4096], BsmH[4096], BsmL[4096];
  char* AHB=(char*)AsmH; char* ALB=(char*)AsmL;
  char* BHB=(char*)BsmH; char* BLB=(char*)BsmL;
  const int t = threadIdx.x;
  const int m0 = blockIdx.y << 7, n0 = blockIdx.x << 7;
  const int w = t >> 6, l = t & 63;
  const int wr = (w >> 1) << 6, wc = (w & 1) << 6;
  const int lr = l & 15, lg = l >> 4;
  const int srow = t >> 1, sseg = t & 1;
  const int q = (srow >> 1) & 3;
  const int wo0 = srow*64 + ((((sseg<<1)|0) ^ q) << 4);
  const int wo1 = srow*64 + ((((sseg<<1)|1) ^ q) << 4);
  const int am = m0 + srow;
  const size_t aoff = (size_t)(am + padA*(am >> 11))*lda + (sseg << 4);
  const u16* AhP = Ah + aoff;
  const u16* AlP = Al + aoff;
  const size_t boff = (size_t)(n0 + srow)*ldb + (sseg << 4);
  const u16* BhP = Bh + boff;
  const u16* BlP = Bl + boff;
  const int qa = ((wr + lr) >> 1) & 3, qb = ((wc + lr) >> 1) & 3;
  const int raBase = (wr + lr)*64 + ((lg ^ qa) << 4);
  const int rbBase = (wc + lr)*64 + ((lg ^ qb) << 4);
  f32x4 acc[4][4];
#pragma unroll
  for (int i=0;i<4;i++)
#pragma unroll
    for (int j=0;j<4;j++) acc[i][j] = (f32x4){0.f,0.f,0.f,0.f};

  for (int k0 = 0; k0 < K; k0 += 32){
    float4 ah0 = *(const float4*)(AhP + k0);
    float4 ah1 = *(const float4*)(AhP + k0 + 8);
    float4 al0 = *(const float4*)(AlP + k0);
    float4 al1 = *(const float4*)(AlP + k0 + 8);
    float4 bh0 = *(const float4*)(BhP + k0);
    float4 bh1 = *(const float4*)(BhP + k0 + 8);
    float4 bl0 = *(const float4*)(BlP + k0);
    float4 bl1 = *(const float4*)(BlP + k0 + 8);
    __syncthreads();
    *(float4*)(AHB + wo0) = ah0;  *(float4*)(AHB + wo1) = ah1;
    *(float4*)(ALB + wo0) = al0;  *(float4*)(ALB + wo1) = al1;
    *(float4*)(BHB + wo0) = bh0;  *(float4*)(BHB + wo1) = bh1;
    *(float4*)(BLB + wo0) = bl0;  *(float4*)(BLB + wo1) = bl1;
    __syncthreads();
    short8v fah[4], fal[4], fbh[4], fbl[4];
#pragma unroll
    for (int i=0;i<4;i++){
      fah[i] = *(short8v*)(AHB + raBase + i*1024);
      fal[i] = *(short8v*)(ALB + raBase + i*1024);
    }
#pragma unroll
    for (int j=0;j<4;j++){
      fbh[j] = *(short8v*)(BHB + rbBase + j*1024);
      fbl[j] = *(short8v*)(BLB + rbBase + j*1024);
    }
#pragma unroll
    for (int i=0;i<4;i++)
#pragma unroll
      for (int j=0;j<4;j++){
        acc[i][j] = __builtin_amdgcn_mfma_f32_16x16x32_bf16(fah[i], fbh[j], acc[i][j], 0, 0, 0);
        acc[i][j] = __builtin_amdgcn_mfma_f32_16x16x32_bf16(fal[i], fbh[j], acc[i][j], 0, 0, 0);
        acc[i][j] = __builtin_amdgcn_mfma_f32_16x16x32_bf16(fah[i], fbl[j], acc[i][j], 0, 0, 0);
      }
  }

#pragma unroll
  for (int i=0;i<4;i++){
    int mbase = m0 + wr + i*16 + (lg << 2);
#pragma unroll
    for (int j=0;j<4;j++){
      int nn = n0 + wc + j*16 + lr;
      float bs = bias[nn];
      f32x4 v = acc[i][j];
#pragma unroll
      for (int r=0;r<4;r++){
        int m = mbase + r;
        float x = v[r] + bs;
        if (EPI == 1) x += cnd[((m >> 11) << 8) + nn];
        if (EPI == 2) x = tanhf(x);
        if (EPI == 3) x += cnd[(size_t)m*256 + 128 + nn];   // + x1
        size_t ro = (size_t)(m + padC*(m >> 11))*ldc + nn;
        if (SPLITOUT){
          u16 xh = f2bf(x);
          ((u16*)CH)[ro] = xh;
          ((u16*)CL)[ro] = f2bf(x - bf2f(xh));
        } else {
          ((float*)CH)[ro] = x;
        }
      }
    }
  }
}

// x0 pass-through: zdst[:,128:] = zsrc[:,:128]
__global__ void k_x0copy(const float* __restrict__ src, float* __restrict__ dst){
  size_t i = ((size_t)blockIdx.x*256 + threadIdx.x) << 2;
  size_t row = i >> 7; int c = (int)(i & 127);
  *(float4*)(dst + row*256 + 128 + c) = *(const float4*)(src + row*256 + c);
}

// ---------------- MAS: producer/consumer LDS pipeline ----------------
#define MCH 8
#define NCHK (TZ_/MCH)
__device__ __forceinline__ void mas_rows(const float* __restrict__ bp, int ch, float* Q,
                                         int ln, unsigned char* __restrict__ cb){
  for (int rr = 0; rr < MCH; rr++){
    int tr = ch*MCH + rr;
    if (tr == 0){
      float q0 = bp[0];
      if (ln == 0) Q[0] = q0;
      continue;
    }
    float4 u0 = *(const float4*)(bp + rr*TT_ + ln*8);
    float4 u1 = *(const float4*)(bp + rr*TT_ + ln*8 + 4);
    float v[8] = {u0.x,u0.y,u0.z,u0.w,u1.x,u1.y,u1.z,u1.w};
    float qp = __shfl_up(Q[7], 1);
    if (ln == 0) qp = NEGF;
    unsigned bits = 0; float qs = qp;
#pragma unroll
    for (int i=0;i<8;i++){
      float old = Q[i];
      if (qs > old) bits |= (1u<<i);
      Q[i] = v[i] + fmaxf(old, qs);
      qs = old;
    }
    cb[(size_t)(tr-1)*64 + ln] = (unsigned char)bits;
  }
}

__global__ __launch_bounds__(512) void k_mas(const float* __restrict__ lp,
  const int* __restrict__ text, unsigned char* __restrict__ cho, int* __restrict__ path)
{
  const int b = blockIdx.x, t = threadIdx.x, ln = t & 63;
  const float* L = lp + (size_t)b*TZ_*TT_;
  __shared__ float buf[3][MCH*TT_];
  __shared__ __align__(16) unsigned char lch[64*64];
  const int frow = t >> 6;
  const int fcol = (t & 63) * 8;
  const size_t gsrc = (size_t)frow*TT_ + fcol;
  unsigned char* cb = cho + (size_t)b*TZ_*64;
  {
    float4 a0 = *(const float4*)(L + gsrc);
    float4 a1 = *(const float4*)(L + gsrc + 4);
    float4 c0 = *(const float4*)(L + (size_t)MCH*TT_ + gsrc);
    float4 c1 = *(const float4*)(L + (size_t)MCH*TT_ + gsrc + 4);
    *(float4*)&buf[0][(size_t)frow*TT_+fcol]   = a0;
    *(float4*)&buf[0][(size_t)frow*TT_+fcol+4] = a1;
    *(float4*)&buf[1][(size_t)frow*TT_+fcol]   = c0;
    *(float4*)&buf[1][(size_t)frow*TT_+fcol+4] = c1;
  }
  float4 pA0 = *(const float4*)(L + (size_t)2*MCH*TT_ + gsrc);
  float4 pA1 = *(const float4*)(L + (size_t)2*MCH*TT_ + gsrc + 4);
  float4 pB0 = *(const float4*)(L + (size_t)3*MCH*TT_ + gsrc);
  float4 pB1 = *(const float4*)(L + (size_t)3*MCH*TT_ + gsrc + 4);
  __syncthreads();
  float Q[8];
#pragma unroll
  for (int i=0;i<8;i++) Q[i] = NEGF;
  int cur = 0;
#define MAS_STEP(CH, P0, P1) do { \
    int wslot = cur + 2; if (wslot >= 3) wslot -= 3; \
    if ((CH) + 2 < NCHK){ \
      *(float4*)&buf[wslot][(size_t)frow*TT_+fcol]   = P0; \
      *(float4*)&buf[wslot][(size_t)frow*TT_+fcol+4] = P1; \
    } \
    if ((CH) + 4 < NCHK){ \
      P0 = *(const float4*)(L + (size_t)((CH)+4)*MCH*TT_ + gsrc); \
      P1 = *(const float4*)(L + (size_t)((CH)+4)*MCH*TT_ + gsrc + 4); \
    } \
    if (t < 64) mas_rows(&buf[cur][0], (CH), Q, ln, cb); \
    __syncthreads(); \
    cur++; if (cur >= 3) cur = 0; \
  } while(0)
  for (int ch = 0; ch < NCHK; ch += 2){
    MAS_STEP(ch,   pA0, pA1);
    MAS_STEP(ch+1, pB0, pB1);
  }
#undef MAS_STEP
  int j = 0;
  if (t < 64){
    int cnt = 0;
#pragma unroll
    for (int i=0;i<8;i++) cnt += (text[b*TT_ + ln*8 + i] != 0) ? 1 : 0;
#pragma unroll
    for (int o2=32;o2;o2>>=1) cnt += __shfl_xor(cnt, o2);
    j = cnt - 1;
  }
  if (t == 0) path[b*TZ_ + TZ_-1] = j;
  __syncthreads();
  for (int tc = TZ_-1; tc >= 1; tc -= 64){
    int ns = min(64, tc);
    if (t < 256){
      int s = t >> 2, c = (t & 3) << 4;
      if (s < ns)
        *(float4*)&lch[s*64 + c] = *(const float4*)&cb[(size_t)(tc-1-s)*64 + c];
    }
    __syncthreads();
    if (t == 0){
      for (int s=0;s<ns;s++){
        unsigned bits = lch[s*64 + (j>>3)];
        j -= (int)((bits >> (j&7)) & 1u);
        path[b*TZ_ + tc - s - 1] = j;
      }
    }
    __syncthreads();
  }
}

// ---------------- ctx gather + h copy ----------------
__global__ void k_gather(const float* __restrict__ mulv, const int* __restrict__ path,
  const float* __restrict__ h, float* __restrict__ out){
  size_t i = (size_t)blockIdx.x*256 + threadIdx.x;
  const size_t N4 = (size_t)BB*TZ_*(D_/4);
  const size_t H4 = (size_t)BB*TT_*(D_/4);
  if (i < N4){
    size_t row = i >> 6; int c = (int)(i & 63);
    int b = (int)(row >> 11);
    int pj = path[row];
    ((float4*)out)[i] = *(const float4*)(mulv + ((size_t)b*TT_ + pj)*512 + (size_t)c*4);
  } else if (i < N4 + H4){
    size_t k2 = i - N4;
    ((float4*)out)[i] = ((const float4*)h)[k2];
  }
}

extern "C" void kernel_launch(void* const* d_in, const int* in_sizes, int n_in,
                              void* d_out, int out_size, void* d_ws, size_t ws_size,
                              hipStream_t stream)
{
  (void)in_sizes; (void)n_in; (void)out_size; (void)ws_size;
  const float* z      = (const float*)d_in[0];
  const int*   text   = (const int*)  d_in[1];
  const float* cond   = (const float*)d_in[2];
  const float* emb    = (const float*)d_in[3];
  const float* wq     = (const float*)d_in[4];
  const float* wk     = (const float*)d_in[5];
  const float* wv     = (const float*)d_in[6];
  const float* wo     = (const float*)d_in[7];
  const float* bq     = (const float*)d_in[8];
  const float* bk     = (const float*)d_in[9];
  const float* bv     = (const float*)d_in[10];
  const float* bo     = (const float*)d_in[11];
  const float* ln1g   = (const float*)d_in[12];
  const float* ln1b   = (const float*)d_in[13];
  const float* ln2g   = (const float*)d_in[14];
  const float* ln2b   = (const float*)d_in[15];
  const float* w1     = (const float*)d_in[16];
  const float* b1     = (const float*)d_in[17];
  const float* w2     = (const float*)d_in[18];
  const float* b2     = (const float*)d_in[19];
  const float* mu_w   = (const float*)d_in[20];
  const float* mu_b   = (const float*)d_in[21];
  const float* lv_w   = (const float*)d_in[22];
  const float* lv_b   = (const float*)d_in[23];
  const float* f_in   = (const float*)d_in[24];
  const float* f_in_b = (const float*)d_in[25];
  const float* f_cond = (const float*)d_in[26];
  const float* f_conv = (const float*)d_in[27];
  const float* f_convb= (const float*)d_in[28];
  const float* f_out  = (const float*)d_in[29];
  const float* f_outb = (const float*)d_in[30];

  // ---- lean workspace: 59,297,792 floats = 237,191,168 B (< 237.7MB proven) ----
  float* ws = (float*)d_ws;
  size_t o = 0;
  float* PE   = ws + o; o += (size_t)131072;
  float* H    = ws + o; o += (size_t)2097152;
  float* MULV = ws + o; o += (size_t)4194304;
  float* NC1  = ws + o; o += (size_t)8192;
  float* NC4  = ws + o; o += (size_t)8192;
  float* CONDP= ws + o; o += (size_t)4096;
  int*   PATH = (int*)(ws + o); o += (size_t)32768;
  u16*  B2H  = (u16*)(ws + o); o += (size_t)2097152;
  u16*  B2L  = (u16*)(ws + o); o += (size_t)2097152;
  float* BIGS = ws + o; o += (size_t)16777216;   // scores / FFN hidden / Xp / logp
  float* BUF1 = ws + o; o += (size_t)4587520;    // flows: X0 planes + flow weights
  float* BUF2 = ws + o; o += (size_t)10485760;   // encoder QKV|Yb|VT (ATTO=QKV); flows H2
  float* ZCA  = ws + o; o += (size_t)8388608;    // init: weightsT; flows zdst even; mas: CHO
  float* ZCB  = ws + o; o += (size_t)8388608;    // flows zdst odd -> final zc

  // encoder carve of BUF2
  float* QKV = BUF2;
  float* Yb  = QKV + 6291456;
  float* VT  = Yb + 2097152;
  float* ATTO= QKV;                      // alias: QKV dead after av
  // transposed weights in ZCA (consumed before flows overwrite)
  float* QKVT = ZCA;
  float* OT   = QKVT + 1179648;
  float* W1T  = OT + 393216;
  float* W2T  = W1T + 1572864;
  float* MULVT= W2T + 1572864;
  float* BQKV = MULVT + 131072;
  float* MULVB= BQKV + 4608;
  // flow arena
  u16*  X0H = (u16*)BUF1;
  u16*  X0L = X0H + 4194304;
  u16*  WITH = X0L + 4194304;
  u16*  WITL = WITH + 32768;
  u16*  WCTH = WITL + 32768;
  u16*  WCTL = WCTH + 327680;
  u16*  WOTH = WCTL + 327680;
  u16*  WOTL = WOTH + 32768;
  u16*  XpH = (u16*)BIGS;
  u16*  XpL = XpH + 8404992;
  u16*  H2H = (u16*)BUF2;
  u16*  H2L = H2H + 8388608;
  unsigned char* CHO = (unsigned char*)ZCA;   // mas phase only

  k_pe   <<<dim3(TT_),    dim3(D_), 0, stream>>>(PE);
  k_embed<<<dim3(BB*TT_), dim3(D_), 0, stream>>>(text, emb, PE, H);
  k_wt   <<<dim3(16,74), 256, 0, stream>>>(wq,wk,wv,wo,mu_w,lv_w,w1,w2, QKVT,OT,MULVT,W1T,W2T);
  k_bcat <<<dim3(20), 256, 0, stream>>>(bq,bk,bv,mu_b,lv_b, BQKV, MULVB);

  for (int l=0;l<L_;l++){
    k_mg<4,0,0,0><<<dim3(6,64,1),256,0,stream>>>(
      H, nullptr, 256, 0,0,  QKVT + (size_t)l*196608, nullptr, 256, 0,0,
      BQKV + l*768, nullptr, nullptr, nullptr, QKV, 768, 0,0, 256);
    k_vt <<<dim3(4,8,16),256,0,stream>>>(QKV, VT);
    k_mg<4,2,0,0><<<dim3(4,4,64),256,0,stream>>>(
      QKV, nullptr, 768, 393216, 64,  QKV+256, nullptr, 768, 393216, 64,
      nullptr, text, nullptr, nullptr, BIGS, 512, 1048576, 262144, 64);
    k_softmax<<<dim3(BB*HEADS_*TT_),64,0,stream>>>(BIGS);
    k_mg<2,0,0,0><<<dim3(1,4,64),256,0,stream>>>(
      BIGS, nullptr, 512, 1048576, 262144,  VT, nullptr, 512, 131072, 32768,
      nullptr, nullptr, nullptr, nullptr, Yb, 256, 131072, 64, 512);
    k_mg<4,0,0,0><<<dim3(2,64,1),256,0,stream>>>(
      Yb, nullptr, 256, 0,0,  OT + (size_t)l*65536, nullptr, 256, 0,0,
      bo + l*256, nullptr, nullptr, nullptr, ATTO, 256, 0,0, 256);
    k_lnres<<<dim3(BB*TT_),256,0,stream>>>(ATTO, ln1g+l*D_, ln1b+l*D_, H);
    k_mg<4,1,0,0><<<dim3(8,64,1),256,0,stream>>>(
      H, nullptr, 256, 0,0,  W1T + (size_t)l*262144, nullptr, 256, 0,0,
      b1 + l*1024, nullptr, nullptr, nullptr, BIGS, 1024, 0,0, 256);
    k_mg<4,0,0,0><<<dim3(2,64,1),256,0,stream>>>(
      BIGS, nullptr, 1024, 0,0,  W2T + (size_t)l*262144, nullptr, 1024, 0,0,
      b2 + l*256, nullptr, nullptr, nullptr, ATTO, 256, 0,0, 1024);
    k_lnres<<<dim3(BB*TT_),256,0,stream>>>(ATTO, ln2g+l*D_, ln2b+l*D_, H);
  }

  k_mg<4,0,0,0><<<dim3(4,64,1),256,0,stream>>>(
    H, nullptr, 256, 0,0,  MULVT, nullptr, 256, 0,0,
    MULVB, nullptr, nullptr, nullptr, MULV, 512, 0,0, 256);
  k_prep<<<dim3(BB*TT_),256,0,stream>>>(MULV, B2H, B2L, NC1, NC4);

  // ---- flows (split-bf16 MFMA, fused flowmix) ----
  k_padzero2<<<dim3(128),256,0,stream>>>(XpH, XpL);
  const float* zsrc = z;
  for (int f=0; f<FLOWS_; f++){
    k_condproj<<<dim3(BB),256,0,stream>>>(cond, f_cond + (size_t)f*G_*HID_, CONDP);
    k_wprep2<<<dim3(1536),256,0,stream>>>(f_in + (size_t)f*(CH_/2)*HID_,
                                          f_conv + (size_t)f*KCV*HID_*HID_,
                                          f_out + (size_t)f*HID_*(CH_/2),
                                          WITH, WITL, WCTH, WCTL, WOTH, WOTL);
    k_x0prep2<<<dim3(2048),256,0,stream>>>(zsrc, X0H, X0L);
    k_mf2<1,1><<<dim3(2,256),256,0,stream>>>(X0H, X0L, 128, 0, WITH, WITL, 128,
        f_in_b + f*HID_, CONDP, (void*)(XpH + 512), (void*)(XpL + 512), 256, 4, 128);
    k_mf2<2,1><<<dim3(2,256),256,0,stream>>>(XpH, XpL, 256, 4, WCTH, WCTL, 1280,
        f_convb + f*HID_, nullptr, (void*)H2H, (void*)H2L, 256, 0, 1280);
    float* zdst = (f & 1) ? ZCB : ZCA;
    // m + x1 -> zdst[:, :128]  (fused flowmix)
    k_mf2<3,0><<<dim3(1,256),256,0,stream>>>(H2H, H2L, 256, 0, WOTH, WOTL, 256,
        f_outb + f*(CH_/2), zsrc, (void*)zdst, nullptr, 256, 0, 256);
    // x0 -> zdst[:, 128:]
    k_x0copy<<<dim3(4096),256,0,stream>>>(zsrc, zdst);
    zsrc = zdst;
  }

  // logp: [zc | -0.5 zc^2] @ [msp | spr]^T + nc1+nc4, masked
  k_mg<4,3,2,1><<<dim3(4,16,16),256,0,stream>>>(
    zsrc, nullptr, 256, 2097152, 524288,
    B2H, B2L, 512, 1048576, 262144,
    nullptr, text, NC1, NC4, BIGS, 512, 4194304, 1048576, 512);

  k_mas<<<dim3(BB),512,0,stream>>>(BIGS, text, CHO, PATH);
  k_gather<<<dim3((BB*TZ_*D_/4 + BB*TT_*D_/4)/256),256,0,stream>>>(MULV, PATH, H, (float*)d_out);
}